// Round 1
// baseline (1185.567 us; speedup 1.0000x reference)
//
#include <hip/hip_runtime.h>

#define LRELU 0.01f

// ---------------- problem constants ----------------
static const int kNU = 50000, kNN = 20000, kNS = 2000;
// relations: 0 follows U->U, 1 posts U->N, 2 posted_by N->U, 3 publishes S->N, 4 published_by N->S
static const int REL_NSRC[5] = {kNU, kNU, kNN, kNS, kNN};
static const int REL_NDST[5] = {kNU, kNN, kNU, kNN, kNS};
static const int REL_E[5]    = {500000, 300000, 300000, 150000, 150000};
// degree-count layout (ints/floats): dout_f,din_f,dout_p,din_p,dout_pb,din_pb,dout_pub,din_pub,dout_pubby,din_pubby
static const int DOUT_OFF[5] = {0, 100000, 170000, 240000, 262000};
static const int DIN_OFF[5]  = {50000, 150000, 190000, 242000, 282000};
static const int CNT_TOT     = 284000;
static const int CUR_OFF[5]  = {0, 50000, 70000, 120000, 140000};       // per-relation n_dst
static const int CUR_TOT     = 142000;
static const int RP_OFF[5]   = {0, 50001, 70002, 120003, 140004};      // n_dst+1 each
static const int CSR_OFF[5]  = {0, 500000, 800000, 1100000, 1250000};

// ---------------- kernels ----------------

__global__ __launch_bounds__(256) void k_count(const int* __restrict__ src,
    const int* __restrict__ dst, int* __restrict__ dout, int* __restrict__ din, int E) {
  int i = blockIdx.x * 256 + threadIdx.x;
  int stride = gridDim.x * 256;
  for (; i < E; i += stride) {
    atomicAdd(&dout[src[i]], 1);
    atomicAdd(&din[dst[i]], 1);
  }
}

__global__ __launch_bounds__(256) void k_rs(const int* __restrict__ cnt,
                                            float* __restrict__ rs, int n) {
  int i = blockIdx.x * 256 + threadIdx.x;
  if (i < n) {
    int c = cnt[i];
    rs[i] = rsqrtf((float)(c > 1 ? c : 1));
  }
}

struct ScanArgs { const int* cnt[5]; int* rp[5]; int n[5]; };

// one block per relation: exclusive scan of din counts -> row_ptr
__global__ __launch_bounds__(256) void k_scan(ScanArgs a) {
  int b = blockIdx.x;
  const int* cnt = a.cnt[b];
  int* rp = a.rp[b];
  int n = a.n[b];
  __shared__ int sd[256];
  int t = threadIdx.x;
  int running = 0;
  for (int base = 0; base < n; base += 256) {
    int v = (base + t < n) ? cnt[base + t] : 0;
    sd[t] = v;
    __syncthreads();
    for (int s = 1; s < 256; s <<= 1) {
      int add = (t >= s) ? sd[t - s] : 0;
      __syncthreads();
      sd[t] += add;
      __syncthreads();
    }
    if (base + t < n) rp[base + t] = running + sd[t] - v;
    running += sd[255];
    __syncthreads();
  }
  if (t == 0) rp[n] = running;
}

__global__ __launch_bounds__(256) void k_fill(const int* __restrict__ src,
    const int* __restrict__ dst, const int* __restrict__ rp,
    int* __restrict__ cur, int* __restrict__ csr, int E) {
  int i = blockIdx.x * 256 + threadIdx.x;
  int stride = gridDim.x * 256;
  for (; i < E; i += stride) {
    int d = dst[i];
    int p = atomicAdd(&cur[d], 1);
    csr[rp[d] + p] = src[i];
  }
}

// C[M x NTOT slice 64] = (diag(rowscale) * A[M x 128]) @ W[128 x NTOT] (+bias)
// block: 64 rows x 64 cols, 256 threads, 4x4 micro-tile. LDS = 32KB W + 32KB A (XOR-swizzled).
template <int NTOT>
__global__ __launch_bounds__(256) void k_gemm(const float* __restrict__ A,
    const float* __restrict__ rowscale, const float* __restrict__ W,
    const float* __restrict__ bias, float* __restrict__ C, int M) {
  __shared__ float Wsh[128 * 64];
  __shared__ float Ash[64 * 128];
  int t = threadIdx.x;
  int m0 = blockIdx.x * 64;
  int n0 = blockIdx.y * 64;
  // stage W slice (128 x 64)
  for (int i = t; i < 128 * 16; i += 256) {
    int r = i >> 4, c4 = i & 15;
    *(float4*)&Wsh[r * 64 + c4 * 4] = *(const float4*)&W[r * NTOT + n0 + c4 * 4];
  }
  // stage A tile (64 x 128), row-scaled, XOR-swizzled on float4 granules
  for (int i = t; i < 64 * 32; i += 256) {
    int r = i >> 5, c4 = i & 31;
    int row = m0 + r;
    float4 a = {0.f, 0.f, 0.f, 0.f};
    if (row < M) {
      a = *(const float4*)&A[row * 128 + c4 * 4];
      if (rowscale) {
        float s = rowscale[row];
        a.x *= s; a.y *= s; a.z *= s; a.w *= s;
      }
    }
    int c4s = c4 ^ ((r >> 2) & 3);
    *(float4*)&Ash[r * 128 + c4s * 4] = a;
  }
  __syncthreads();
  int tx = t & 15, ty = t >> 4;
  int sw = ty & 3;
  float acc[4][4] = {};
#pragma unroll 8
  for (int k = 0; k < 128; ++k) {
    float4 w = *(const float4*)&Wsh[k * 64 + tx * 4];
    int kidx = (((k >> 2) ^ sw) << 2) | (k & 3);
#pragma unroll
    for (int i = 0; i < 4; ++i) {
      float av = Ash[(ty * 4 + i) * 128 + kidx];
      acc[i][0] += av * w.x;
      acc[i][1] += av * w.y;
      acc[i][2] += av * w.z;
      acc[i][3] += av * w.w;
    }
  }
#pragma unroll
  for (int i = 0; i < 4; ++i) {
    int row = m0 + ty * 4 + i;
    if (row < M) {
      float4 o = {acc[i][0], acc[i][1], acc[i][2], acc[i][3]};
      if (bias) {
        float4 b = *(const float4*)&bias[n0 + tx * 4];
        o.x += b.x; o.y += b.y; o.z += b.z; o.w += b.w;
      }
      *(float4*)&C[row * NTOT + n0 + tx * 4] = o;
    }
  }
}

// one wave per dst row: agg[d] (+)= rsqrt(din[d]) * sum_{e in bucket(d)} H[src[e]]
__global__ __launch_bounds__(256) void k_gather(const int* __restrict__ rp,
    const int* __restrict__ csr, const float* __restrict__ H,
    const float* __restrict__ rs_din, float* __restrict__ agg,
    int n_dst, int accumulate) {
  int wid = (blockIdx.x * 256 + threadIdx.x) >> 6;
  int lane = threadIdx.x & 63;
  if (wid >= n_dst) return;
  int e0 = rp[wid], e1 = rp[wid + 1];
  float ax = 0.f, ay = 0.f;
  for (int e = e0; e < e1; ++e) {
    int s = csr[e];
    float2 v = *(const float2*)&H[s * 128 + lane * 2];
    ax += v.x;
    ay += v.y;
  }
  float sc = rs_din[wid];
  float2* d = (float2*)&agg[wid * 128 + lane * 2];
  if (accumulate) {
    float2 old = *d;
    old.x += ax * sc;
    old.y += ay * sc;
    *d = old;
  } else {
    float2 o = {ax * sc, ay * sc};
    *d = o;
  }
}

// out = lrelu(scale * (agg + b1 [+ b2])), rows of 128
__global__ __launch_bounds__(256) void k_combine(float* __restrict__ out,
    const float* __restrict__ agg, const float* __restrict__ b1,
    const float* __restrict__ b2, float scale, int n4tot) {
  int i = blockIdx.x * 256 + threadIdx.x;
  if (i >= n4tot) return;
  int c4 = i & 31;
  float4 v = ((const float4*)agg)[i];
  float4 ba = ((const float4*)b1)[c4];
  v.x += ba.x; v.y += ba.y; v.z += ba.z; v.w += ba.w;
  if (b2) {
    float4 bb = ((const float4*)b2)[c4];
    v.x += bb.x; v.y += bb.y; v.z += bb.z; v.w += bb.w;
  }
  v.x *= scale; v.y *= scale; v.z *= scale; v.w *= scale;
  v.x = v.x >= 0.f ? v.x : LRELU * v.x;
  v.y = v.y >= 0.f ? v.y : LRELU * v.y;
  v.z = v.z >= 0.f ? v.z : LRELU * v.z;
  v.w = v.w >= 0.f ? v.w : LRELU * v.w;
  ((float4*)out)[i] = v;
}

// ---------------- host ----------------

extern "C" void kernel_launch(void* const* d_in, const int* in_sizes, int n_in,
                              void* d_out, int out_size, void* d_ws, size_t ws_size,
                              hipStream_t stream) {
  const float* xu = (const float*)d_in[0];
  const float* xn = (const float*)d_in[1];
  const float* xs = (const float*)d_in[2];
  const float* W1 = (const float*)d_in[3];
  const float* b1 = (const float*)d_in[4];
  const float* W2 = (const float*)d_in[5];
  const float* b2 = (const float*)d_in[6];
  const float* Wu = (const float*)d_in[7];
  const float* bu = (const float*)d_in[8];
  const float* Wn = (const float*)d_in[9];
  const float* bn = (const float*)d_in[10];
  const float* Wsrc = (const float*)d_in[11];
  const float* bsrc = (const float*)d_in[12];
  const int* SRC[5] = {(const int*)d_in[13], (const int*)d_in[15], (const int*)d_in[17],
                       (const int*)d_in[19], (const int*)d_in[21]};
  const int* DST[5] = {(const int*)d_in[14], (const int*)d_in[16], (const int*)d_in[18],
                       (const int*)d_in[20], (const int*)d_in[22]};

  // ---- workspace layout (needs ~71.6 MB) ----
  int* ws_i = (int*)d_ws;
  int* cnt = ws_i;                    // 284000
  int* cur = ws_i + CNT_TOT;          // 142000 (contiguous with cnt for one memset)
  int* rp  = ws_i + 426000;           // 142008 (padded)
  int* csr = ws_i + 568008;           // 1400000
  float* wf   = (float*)(ws_i + 1968008);
  float* rs   = wf;                   // 284000
  float* Hbuf = wf + 284000;          // 6.4M (max n_src * 128)
  float* aggU = wf + 6684000;         // 6.4M
  float* aggN = wf + 13084000;        // 2.56M
  float* aggS = wf + 15644000;        // 256K

  // ---- d_out layout ----
  float* outf = (float*)d_out;
  float* ou = outf;                   // 50000*64
  float* on = outf + 3200000;         // 20000*64
  float* osrc = outf + 4480000;       // 2000*64
  float* hu = outf + 4608000;         // 50000*128 (holds h1 then h2)
  float* hn = outf + 11008000;        // 20000*128
  float* hs = outf + 13568000;        // 2000*128

  // ---- graph structure (per call; edges are inputs) ----
  hipMemsetAsync(cnt, 0, (size_t)(CNT_TOT + CUR_TOT) * 4, stream);
  for (int r = 0; r < 5; ++r)
    k_count<<<(REL_E[r] + 255) / 256, 256, 0, stream>>>(SRC[r], DST[r],
        cnt + DOUT_OFF[r], cnt + DIN_OFF[r], REL_E[r]);
  k_rs<<<(CNT_TOT + 255) / 256, 256, 0, stream>>>(cnt, rs, CNT_TOT);
  ScanArgs sa;
  for (int r = 0; r < 5; ++r) {
    sa.cnt[r] = cnt + DIN_OFF[r];
    sa.rp[r] = rp + RP_OFF[r];
    sa.n[r] = REL_NDST[r];
  }
  k_scan<<<5, 256, 0, stream>>>(sa);
  for (int r = 0; r < 5; ++r)
    k_fill<<<(REL_E[r] + 255) / 256, 256, 0, stream>>>(SRC[r], DST[r],
        rp + RP_OFF[r], cur + CUR_OFF[r], csr + CSR_OFF[r], REL_E[r]);

  // ---- hetero layer ----
  auto layer = [&](const float* inU, const float* inN, const float* inS,
                   const float* Wl, const float* bl,
                   float* outU, float* outN, float* outS) {
    const float* XIN[5] = {inU, inU, inN, inS, inN};
    float* AGG[5] = {aggU, aggN, aggU, aggN, aggS};
    const int ACC[5] = {0, 0, 1, 1, 0};
    for (int r = 0; r < 5; ++r) {
      int M = REL_NSRC[r];
      dim3 gg((M + 63) / 64, 2);
      k_gemm<128><<<gg, 256, 0, stream>>>(XIN[r], rs + DOUT_OFF[r],
          Wl + (size_t)r * 128 * 128, nullptr, Hbuf, M);
      int nd = REL_NDST[r];
      k_gather<<<(nd + 3) / 4, 256, 0, stream>>>(rp + RP_OFF[r], csr + CSR_OFF[r],
          Hbuf, rs + DIN_OFF[r], AGG[r], nd, ACC[r]);
    }
    k_combine<<<(kNU * 32 + 255) / 256, 256, 0, stream>>>(outU, aggU,
        bl + 0 * 128, bl + 2 * 128, 0.5f, kNU * 32);
    k_combine<<<(kNN * 32 + 255) / 256, 256, 0, stream>>>(outN, aggN,
        bl + 1 * 128, bl + 3 * 128, 0.5f, kNN * 32);
    k_combine<<<(kNS * 32 + 255) / 256, 256, 0, stream>>>(outS, aggS,
        bl + 4 * 128, nullptr, 1.0f, kNS * 32);
  };

  // layer 1: x -> h1 (stored in d_out's hu/hn/hs slots)
  layer(xu, xn, xs, W1, b1, hu, hn, hs);
  // layer 2: h1 -> h2 (combine overwrites the same slots AFTER all 5 gemms consumed h1)
  layer(hu, hn, hs, W2, b2, hu, hn, hs);

  // output projections
  k_gemm<64><<<dim3((kNU + 63) / 64, 1), 256, 0, stream>>>(hu, nullptr, Wu, bu, ou, kNU);
  k_gemm<64><<<dim3((kNN + 63) / 64, 1), 256, 0, stream>>>(hn, nullptr, Wn, bn, on, kNN);
  k_gemm<64><<<dim3((kNS + 63) / 64, 1), 256, 0, stream>>>(hs, nullptr, Wsrc, bsrc, osrc, kNS);
}

// Round 2
// 839.461 us; speedup vs baseline: 1.4123x; 1.4123x over previous
//
#include <hip/hip_runtime.h>

#define LRELU 0.01f

// ---------------- problem constants ----------------
// relations: 0 follows U->U, 1 posts U->N, 2 posted_by N->U, 3 publishes S->N, 4 published_by N->S
static const int kNU = 50000, kNN = 20000, kNS = 2000;
static const int REL_E[5]  = {500000, 300000, 300000, 150000, 150000};
static const int REL_ND[5] = {50000, 20000, 50000, 20000, 2000};
// offsets into cnt/rs arrays
static const int DOUT_OFF[5] = {0, 100000, 170000, 240000, 262000};
static const int DIN_OFF[5]  = {50000, 150000, 190000, 242000, 282000};
static const int CUR_OFF[5]  = {0, 50000, 70000, 120000, 140000};
static const int RP_OFF[5]   = {0, 50001, 70002, 120003, 140004};
static const int CSR_OFF[5]  = {0, 500000, 800000, 1100000, 1250000};

__device__ __forceinline__ float bf2f(unsigned short u) {
  return __uint_as_float(((unsigned)u) << 16);
}
__device__ __forceinline__ unsigned short f2bf(float f) {  // RNE
  unsigned u = __float_as_uint(f);
  u += 0x7FFFu + ((u >> 16) & 1u);
  return (unsigned short)(u >> 16);
}

// ---------------- graph build ----------------

struct RelEdge { const int* src; const int* dst; int* dout; int* din; int E; };
struct EdgeArgs { RelEdge rel[5]; };

__global__ __launch_bounds__(256) void k_count(EdgeArgs a) {
  constexpr int ESTART[6] = {0, 1954, 3126, 4298, 4884, 5470};
  int bx = blockIdx.x, r = 0;
  while (bx >= ESTART[r + 1]) ++r;
  RelEdge e = a.rel[r];
  int i = (bx - ESTART[r]) * 256 + threadIdx.x;
  if (i < e.E) {
    atomicAdd(&e.dout[e.src[i]], 1);
    atomicAdd(&e.din[e.dst[i]], 1);
  }
}

__global__ __launch_bounds__(256) void k_rs(const int* __restrict__ cnt,
                                            float* __restrict__ rs, int n) {
  int i = blockIdx.x * 256 + threadIdx.x;
  if (i < n) {
    int c = cnt[i];
    rs[i] = rsqrtf((float)(c > 1 ? c : 1));
  }
}

struct ScanArgs { const int* cnt[5]; int* rp[5]; int n[5]; int* csums; };

// phase 1: per-1024-chunk sums
__global__ __launch_bounds__(256) void k_scan1(ScanArgs a) {
  constexpr int CSTART[6] = {0, 49, 69, 118, 138, 140};
  int bx = blockIdx.x, r = 0;
  while (bx >= CSTART[r + 1]) ++r;
  int chunk = bx - CSTART[r];
  int n = a.n[r];
  int base = chunk * 1024;
  const int* cnt = a.cnt[r];
  int t = threadIdx.x;
  int s = 0;
#pragma unroll
  for (int j = 0; j < 4; ++j) {
    int idx = base + j * 256 + t;
    if (idx < n) s += cnt[idx];
  }
  __shared__ int sd[256];
  sd[t] = s;
  __syncthreads();
  for (int off = 128; off > 0; off >>= 1) {
    if (t < off) sd[t] += sd[t + off];
    __syncthreads();
  }
  if (t == 0) a.csums[r * 64 + chunk] = sd[0];
}

// phase 2: exclusive scan of chunk sums (tiny), write rp[n]
__global__ __launch_bounds__(64) void k_scan2(ScanArgs a) {
  constexpr int NCH[5] = {49, 20, 49, 20, 2};
  int r = threadIdx.x;
  if (r < 5) {
    int run = 0;
    for (int i = 0; i < NCH[r]; ++i) {
      int v = a.csums[r * 64 + i];
      a.csums[r * 64 + i] = run;
      run += v;
    }
    a.rp[r][a.n[r]] = run;
  }
}

// phase 3: local exclusive scan + chunk offset -> rp
__global__ __launch_bounds__(256) void k_scan3(ScanArgs a) {
  constexpr int CSTART[6] = {0, 49, 69, 118, 138, 140};
  int bx = blockIdx.x, r = 0;
  while (bx >= CSTART[r + 1]) ++r;
  int chunk = bx - CSTART[r];
  int n = a.n[r];
  int base = chunk * 1024;
  const int* cnt = a.cnt[r];
  int* rp = a.rp[r];
  int t = threadIdx.x;
  int idx0 = base + t * 4;
  int v[4];
#pragma unroll
  for (int j = 0; j < 4; ++j) v[j] = (idx0 + j < n) ? cnt[idx0 + j] : 0;
  int tsum = v[0] + v[1] + v[2] + v[3];
  __shared__ int sd[256];
  sd[t] = tsum;
  __syncthreads();
  for (int s = 1; s < 256; s <<= 1) {
    int add = (t >= s) ? sd[t - s] : 0;
    __syncthreads();
    sd[t] += add;
    __syncthreads();
  }
  int off = a.csums[r * 64 + chunk] + sd[t] - tsum;
#pragma unroll
  for (int j = 0; j < 4; ++j) {
    if (idx0 + j < n) rp[idx0 + j] = off;
    off += v[j];
  }
}

struct RelFill { const int* src; const int* dst; const int* rp; int* cur; int* csr; int E; };
struct FillArgs { RelFill rel[5]; };

__global__ __launch_bounds__(256) void k_fill(FillArgs a) {
  constexpr int ESTART[6] = {0, 1954, 3126, 4298, 4884, 5470};
  int bx = blockIdx.x, r = 0;
  while (bx >= ESTART[r + 1]) ++r;
  RelFill f = a.rel[r];
  int i = (bx - ESTART[r]) * 256 + threadIdx.x;
  if (i < f.E) {
    int d = f.dst[i];
    int p = atomicAdd(&f.cur[d], 1);
    f.csr[f.rp[d] + p] = f.src[i];
  }
}

// ---------------- aggregate (gather raw features, write bf16) ----------------

struct RelG {
  const int* rp; const int* csr; const float* x;
  const float* rso; const float* rsi;
  unsigned short* out; int stride; int ooff; int nd;
};
struct GArgs { RelG rel[5]; };

__global__ __launch_bounds__(256) void k_gather(GArgs a) {
  constexpr int GSTART[6] = {0, 12500, 17500, 30000, 35000, 35500};
  int bx = blockIdx.x, r = 0;
  while (bx >= GSTART[r + 1]) ++r;
  RelG g = a.rel[r];
  int wid = (bx - GSTART[r]) * 4 + (threadIdx.x >> 6);
  if (wid >= g.nd) return;
  int lane = threadIdx.x & 63;
  int e0 = g.rp[wid], e1 = g.rp[wid + 1];
  float ax = 0.f, ay = 0.f;
  for (int e = e0; e < e1; ++e) {
    int s = g.csr[e];
    float sc = g.rso[s];
    float2 v = *(const float2*)&g.x[(size_t)s * 128 + lane * 2];
    ax = fmaf(v.x, sc, ax);
    ay = fmaf(v.y, sc, ay);
  }
  float si = g.rsi[wid];
  ushort2 o;
  o.x = f2bf(ax * si);
  o.y = f2bf(ay * si);
  *(ushort2*)&g.out[(size_t)wid * g.stride + g.ooff + lane * 2] = o;
}

// ---------------- layer GEMM: H = lrelu(scale*(A @ [W0;W1] + b0 + b1)) ----------------
// A: M x (KCH*128) bf16. W0/W1: 128x128 f32. H: M x 128 f32.
// block = 64 rows x 64 cols, 256 threads, 4x4 micro-tile. LDS 64KB.

template <int KCH>
__global__ __launch_bounds__(256) void k_lgemm(const unsigned short* __restrict__ A,
    const float* __restrict__ W0, const float* __restrict__ W1,
    const float* __restrict__ b0, const float* __restrict__ b1,
    float scale, float* __restrict__ H, int M) {
  __shared__ float Wsh[128 * 64];
  __shared__ float Ash[64 * 128];
  const int ASTRIDE = KCH * 128;
  int t = threadIdx.x;
  int m0 = blockIdx.x * 64;
  int n0 = blockIdx.y * 64;
  int tx = t & 15, ty = t >> 4, sw = ty & 3;
  float acc[4][4] = {};
  for (int c = 0; c < KCH; ++c) {
    const float* Wc = (c == 0) ? W0 : W1;
    for (int i = t; i < 128 * 16; i += 256) {
      int r = i >> 4, c4 = i & 15;
      *(float4*)&Wsh[r * 64 + c4 * 4] = *(const float4*)&Wc[r * 128 + n0 + c4 * 4];
    }
    for (int i = t; i < 64 * 32; i += 256) {
      int r = i >> 5, g = i & 31;
      int row = m0 + r;
      float4 v = {0.f, 0.f, 0.f, 0.f};
      if (row < M) {
        ushort4 u = *(const ushort4*)&A[(size_t)row * ASTRIDE + c * 128 + g * 4];
        v.x = bf2f(u.x); v.y = bf2f(u.y); v.z = bf2f(u.z); v.w = bf2f(u.w);
      }
      int gs = g ^ ((r >> 2) & 3);
      *(float4*)&Ash[r * 128 + gs * 4] = v;
    }
    __syncthreads();
#pragma unroll 8
    for (int k = 0; k < 128; ++k) {
      float4 w = *(const float4*)&Wsh[k * 64 + tx * 4];
      int kidx = (((k >> 2) ^ sw) << 2) | (k & 3);
#pragma unroll
      for (int i = 0; i < 4; ++i) {
        float av = Ash[(ty * 4 + i) * 128 + kidx];
        acc[i][0] += av * w.x;
        acc[i][1] += av * w.y;
        acc[i][2] += av * w.z;
        acc[i][3] += av * w.w;
      }
    }
    __syncthreads();
  }
  float4 bv = *(const float4*)&b0[n0 + tx * 4];
  if (b1) {
    float4 b2v = *(const float4*)&b1[n0 + tx * 4];
    bv.x += b2v.x; bv.y += b2v.y; bv.z += b2v.z; bv.w += b2v.w;
  }
#pragma unroll
  for (int i = 0; i < 4; ++i) {
    int row = m0 + ty * 4 + i;
    if (row < M) {
      float4 o;
      o.x = scale * (acc[i][0] + bv.x);
      o.y = scale * (acc[i][1] + bv.y);
      o.z = scale * (acc[i][2] + bv.z);
      o.w = scale * (acc[i][3] + bv.w);
      o.x = o.x >= 0.f ? o.x : LRELU * o.x;
      o.y = o.y >= 0.f ? o.y : LRELU * o.y;
      o.z = o.z >= 0.f ? o.z : LRELU * o.z;
      o.w = o.w >= 0.f ? o.w : LRELU * o.w;
      *(float4*)&H[(size_t)row * 128 + n0 + tx * 4] = o;
    }
  }
}

// ---------------- projection GEMM (f32 A, K=128, N=64) ----------------

__global__ __launch_bounds__(256) void k_pgemm(const float* __restrict__ A,
    const float* __restrict__ W, const float* __restrict__ bias,
    float* __restrict__ C, int M) {
  __shared__ float Wsh[128 * 64];
  __shared__ float Ash[64 * 128];
  int t = threadIdx.x;
  int m0 = blockIdx.x * 64;
  for (int i = t; i < 128 * 16; i += 256) {
    int r = i >> 4, c4 = i & 15;
    *(float4*)&Wsh[r * 64 + c4 * 4] = *(const float4*)&W[r * 64 + c4 * 4];
  }
  for (int i = t; i < 64 * 32; i += 256) {
    int r = i >> 5, g = i & 31;
    int row = m0 + r;
    float4 v = {0.f, 0.f, 0.f, 0.f};
    if (row < M) v = *(const float4*)&A[(size_t)row * 128 + g * 4];
    int gs = g ^ ((r >> 2) & 3);
    *(float4*)&Ash[r * 128 + gs * 4] = v;
  }
  __syncthreads();
  int tx = t & 15, ty = t >> 4, sw = ty & 3;
  float acc[4][4] = {};
#pragma unroll 8
  for (int k = 0; k < 128; ++k) {
    float4 w = *(const float4*)&Wsh[k * 64 + tx * 4];
    int kidx = (((k >> 2) ^ sw) << 2) | (k & 3);
#pragma unroll
    for (int i = 0; i < 4; ++i) {
      float av = Ash[(ty * 4 + i) * 128 + kidx];
      acc[i][0] += av * w.x;
      acc[i][1] += av * w.y;
      acc[i][2] += av * w.z;
      acc[i][3] += av * w.w;
    }
  }
  float4 bv = *(const float4*)&bias[tx * 4];
#pragma unroll
  for (int i = 0; i < 4; ++i) {
    int row = m0 + ty * 4 + i;
    if (row < M) {
      float4 o = {acc[i][0] + bv.x, acc[i][1] + bv.y, acc[i][2] + bv.z, acc[i][3] + bv.w};
      *(float4*)&C[(size_t)row * 64 + tx * 4] = o;
    }
  }
}

// ---------------- host ----------------

extern "C" void kernel_launch(void* const* d_in, const int* in_sizes, int n_in,
                              void* d_out, int out_size, void* d_ws, size_t ws_size,
                              hipStream_t stream) {
  const float* xu = (const float*)d_in[0];
  const float* xn = (const float*)d_in[1];
  const float* xs = (const float*)d_in[2];
  const float* W1 = (const float*)d_in[3];
  const float* b1 = (const float*)d_in[4];
  const float* W2 = (const float*)d_in[5];
  const float* b2 = (const float*)d_in[6];
  const float* Wu = (const float*)d_in[7];
  const float* bu = (const float*)d_in[8];
  const float* Wn = (const float*)d_in[9];
  const float* bn = (const float*)d_in[10];
  const float* Wsrc = (const float*)d_in[11];
  const float* bsrc = (const float*)d_in[12];
  const int* SRC[5] = {(const int*)d_in[13], (const int*)d_in[15], (const int*)d_in[17],
                       (const int*)d_in[19], (const int*)d_in[21]};
  const int* DST[5] = {(const int*)d_in[14], (const int*)d_in[16], (const int*)d_in[18],
                       (const int*)d_in[20], (const int*)d_in[22]};

  // ---- workspace layout (~45.4 MB) ----
  int* ws_i = (int*)d_ws;
  int* cnt = ws_i;                         // 284000
  int* cur = ws_i + 284000;                // 142000 (contiguous with cnt: one memset)
  int* rp = ws_i + 426000;                 // 142008
  int* csr = ws_i + 568008;                // 1400000
  int* csums = ws_i + 1968008;             // 320
  float* rs = (float*)(ws_i + 1968328);    // 284000
  unsigned short* aggU = (unsigned short*)(rs + 284000);  // 50000*256
  unsigned short* aggN = aggU + 12800000;                 // 20000*256
  unsigned short* aggS = aggN + 5120000;                  // 2000*128

  // ---- d_out layout ----
  float* outf = (float*)d_out;
  float* ou = outf;                 // 50000*64
  float* on = outf + 3200000;       // 20000*64
  float* osrc = outf + 4480000;     // 2000*64
  float* hu = outf + 4608000;       // 50000*128
  float* hn = outf + 11008000;      // 20000*128
  float* hs = outf + 13568000;      // 2000*128

  // ---- graph build ----
  hipMemsetAsync(cnt, 0, (size_t)426000 * 4, stream);
  EdgeArgs ea;
  for (int r = 0; r < 5; ++r)
    ea.rel[r] = {SRC[r], DST[r], cnt + DOUT_OFF[r], cnt + DIN_OFF[r], REL_E[r]};
  k_count<<<5470, 256, 0, stream>>>(ea);
  k_rs<<<1110, 256, 0, stream>>>(cnt, rs, 284000);
  ScanArgs sa;
  for (int r = 0; r < 5; ++r) {
    sa.cnt[r] = cnt + DIN_OFF[r];
    sa.rp[r] = rp + RP_OFF[r];
    sa.n[r] = REL_ND[r];
  }
  sa.csums = csums;
  k_scan1<<<140, 256, 0, stream>>>(sa);
  k_scan2<<<1, 64, 0, stream>>>(sa);
  k_scan3<<<140, 256, 0, stream>>>(sa);
  FillArgs fa;
  for (int r = 0; r < 5; ++r)
    fa.rel[r] = {SRC[r], DST[r], rp + RP_OFF[r], cur + CUR_OFF[r], csr + CSR_OFF[r], REL_E[r]};
  k_fill<<<5470, 256, 0, stream>>>(fa);

  // ---- one hetero layer: gather raw features per relation, then fused GEMMs ----
  auto layer = [&](const float* inU, const float* inN, const float* inS,
                   const float* Wl, const float* bl) {
    const float* XIN[5] = {inU, inU, inN, inS, inN};
    unsigned short* OUT[5] = {aggU, aggN, aggU, aggN, aggS};
    const int OSTR[5] = {256, 256, 256, 256, 128};
    const int OOFF[5] = {0, 0, 128, 128, 0};
    GArgs ga;
    for (int r = 0; r < 5; ++r)
      ga.rel[r] = {rp + RP_OFF[r], csr + CSR_OFF[r], XIN[r], rs + DOUT_OFF[r],
                   rs + DIN_OFF[r], OUT[r], OSTR[r], OOFF[r], REL_ND[r]};
    k_gather<<<35500, 256, 0, stream>>>(ga);
    k_lgemm<2><<<dim3(782, 2), 256, 0, stream>>>(aggU, Wl + 0 * 16384, Wl + 2 * 16384,
        bl + 0 * 128, bl + 2 * 128, 0.5f, hu, kNU);
    k_lgemm<2><<<dim3(313, 2), 256, 0, stream>>>(aggN, Wl + 1 * 16384, Wl + 3 * 16384,
        bl + 1 * 128, bl + 3 * 128, 0.5f, hn, kNN);
    k_lgemm<1><<<dim3(32, 2), 256, 0, stream>>>(aggS, Wl + 4 * 16384, nullptr,
        bl + 4 * 128, nullptr, 1.0f, hs, kNS);
  };

  layer(xu, xn, xs, W1, b1);   // x -> h1 (in d_out h-slots)
  layer(hu, hn, hs, W2, b2);   // h1 -> h2 (same slots; h1 fully consumed by gather)

  // ---- output projections ----
  k_pgemm<<<782, 256, 0, stream>>>(hu, Wu, bu, ou, kNU);
  k_pgemm<<<313, 256, 0, stream>>>(hn, Wn, bn, on, kNN);
  k_pgemm<<<32, 256, 0, stream>>>(hs, Wsrc, bsrc, osrc, kNS);
}

// Round 3
// 653.695 us; speedup vs baseline: 1.8136x; 1.2842x over previous
//
#include <hip/hip_runtime.h>

#define LRELU 0.01f

// ---------------- problem constants ----------------
// relations: 0 follows U->U, 1 posts U->N, 2 posted_by N->U, 3 publishes S->N, 4 published_by N->S
static const int kNU = 50000, kNN = 20000, kNS = 2000;
static const int REL_E[5]  = {500000, 300000, 300000, 150000, 150000};
static const int REL_ND[5] = {50000, 20000, 50000, 20000, 2000};
// offsets into cnt/rs arrays
static const int DOUT_OFF[5] = {0, 100000, 170000, 240000, 262000};
static const int DIN_OFF[5]  = {50000, 150000, 190000, 242000, 282000};
static const int CUR_OFF[5]  = {0, 50000, 70000, 120000, 140000};
static const int RP_OFF[5]   = {0, 50001, 70002, 120003, 140004};
static const int CSR_OFF[5]  = {0, 500000, 800000, 1100000, 1250000};

__device__ __forceinline__ float bf2f(unsigned short u) {
  return __uint_as_float(((unsigned)u) << 16);
}
__device__ __forceinline__ unsigned short f2bf(float f) {  // RNE
  unsigned u = __float_as_uint(f);
  u += 0x7FFFu + ((u >> 16) & 1u);
  return (unsigned short)(u >> 16);
}

// ---------------- graph build ----------------

struct RelEdge { const int* src; const int* dst; int* dout; int* din; int E; };
struct EdgeArgs { RelEdge rel[5]; };

__global__ __launch_bounds__(256) void k_count(EdgeArgs a) {
  constexpr int ESTART[6] = {0, 1954, 3126, 4298, 4884, 5470};
  int bx = blockIdx.x, r = 0;
  while (bx >= ESTART[r + 1]) ++r;
  RelEdge e = a.rel[r];
  int i = (bx - ESTART[r]) * 256 + threadIdx.x;
  if (i < e.E) {
    atomicAdd(&e.dout[e.src[i]], 1);
    atomicAdd(&e.din[e.dst[i]], 1);
  }
}

__global__ __launch_bounds__(256) void k_rs(const int* __restrict__ cnt,
                                            float* __restrict__ rs, int n) {
  int i = blockIdx.x * 256 + threadIdx.x;
  if (i < n) {
    int c = cnt[i];
    rs[i] = rsqrtf((float)(c > 1 ? c : 1));
  }
}

struct ScanArgs { const int* cnt[5]; int* rp[5]; int n[5]; int* csums; };

// phase 1: per-1024-chunk sums
__global__ __launch_bounds__(256) void k_scan1(ScanArgs a) {
  constexpr int CSTART[6] = {0, 49, 69, 118, 138, 140};
  int bx = blockIdx.x, r = 0;
  while (bx >= CSTART[r + 1]) ++r;
  int chunk = bx - CSTART[r];
  int n = a.n[r];
  int base = chunk * 1024;
  const int* cnt = a.cnt[r];
  int t = threadIdx.x;
  int s = 0;
#pragma unroll
  for (int j = 0; j < 4; ++j) {
    int idx = base + j * 256 + t;
    if (idx < n) s += cnt[idx];
  }
  __shared__ int sd[256];
  sd[t] = s;
  __syncthreads();
  for (int off = 128; off > 0; off >>= 1) {
    if (t < off) sd[t] += sd[t + off];
    __syncthreads();
  }
  if (t == 0) a.csums[r * 64 + chunk] = sd[0];
}

// phase 2: exclusive scan of chunk sums (tiny), write rp[n]
__global__ __launch_bounds__(64) void k_scan2(ScanArgs a) {
  constexpr int NCH[5] = {49, 20, 49, 20, 2};
  int r = threadIdx.x;
  if (r < 5) {
    int run = 0;
    for (int i = 0; i < NCH[r]; ++i) {
      int v = a.csums[r * 64 + i];
      a.csums[r * 64 + i] = run;
      run += v;
    }
    a.rp[r][a.n[r]] = run;
  }
}

// phase 3: local exclusive scan + chunk offset -> rp
__global__ __launch_bounds__(256) void k_scan3(ScanArgs a) {
  constexpr int CSTART[6] = {0, 49, 69, 118, 138, 140};
  int bx = blockIdx.x, r = 0;
  while (bx >= CSTART[r + 1]) ++r;
  int chunk = bx - CSTART[r];
  int n = a.n[r];
  int base = chunk * 1024;
  const int* cnt = a.cnt[r];
  int* rp = a.rp[r];
  int t = threadIdx.x;
  int idx0 = base + t * 4;
  int v[4];
#pragma unroll
  for (int j = 0; j < 4; ++j) v[j] = (idx0 + j < n) ? cnt[idx0 + j] : 0;
  int tsum = v[0] + v[1] + v[2] + v[3];
  __shared__ int sd[256];
  sd[t] = tsum;
  __syncthreads();
  for (int s = 1; s < 256; s <<= 1) {
    int add = (t >= s) ? sd[t - s] : 0;
    __syncthreads();
    sd[t] += add;
    __syncthreads();
  }
  int off = a.csums[r * 64 + chunk] + sd[t] - tsum;
#pragma unroll
  for (int j = 0; j < 4; ++j) {
    if (idx0 + j < n) rp[idx0 + j] = off;
    off += v[j];
  }
}

struct RelFill { const int* src; const int* dst; const int* rp; int* cur; int* csr; int E; };
struct FillArgs { RelFill rel[5]; };

__global__ __launch_bounds__(256) void k_fill(FillArgs a) {
  constexpr int ESTART[6] = {0, 1954, 3126, 4298, 4884, 5470};
  int bx = blockIdx.x, r = 0;
  while (bx >= ESTART[r + 1]) ++r;
  RelFill f = a.rel[r];
  int i = (bx - ESTART[r]) * 256 + threadIdx.x;
  if (i < f.E) {
    int d = f.dst[i];
    int p = atomicAdd(&f.cur[d], 1);
    f.csr[f.rp[d] + p] = f.src[i];
  }
}

// ---------------- f32 -> bf16 convert (feature tables) ----------------

__global__ __launch_bounds__(256) void k_f2bf(const float* __restrict__ in,
    unsigned short* __restrict__ out, int n4) {
  int i = blockIdx.x * 256 + threadIdx.x;
  if (i >= n4) return;
  float4 v = ((const float4*)in)[i];
  ushort4 o = {f2bf(v.x), f2bf(v.y), f2bf(v.z), f2bf(v.w)};
  ((ushort4*)out)[i] = o;
}

// ---------------- aggregate (gather bf16 features, write bf16) ----------------

struct RelG {
  const int* rp; const int* csr; const unsigned short* xb;
  const float* rso; const float* rsi;
  unsigned short* out; int stride; int ooff; int nd;
};
struct GArgs { RelG rel[5]; };

__global__ __launch_bounds__(256) void k_gather(GArgs a) {
  constexpr int GSTART[6] = {0, 12500, 17500, 30000, 35000, 35500};
  int bx = blockIdx.x, r = 0;
  while (bx >= GSTART[r + 1]) ++r;
  RelG g = a.rel[r];
  int wid = (bx - GSTART[r]) * 4 + (threadIdx.x >> 6);
  if (wid >= g.nd) return;
  int lane = threadIdx.x & 63;
  int e0 = g.rp[wid], e1 = g.rp[wid + 1];
  float ax = 0.f, ay = 0.f;
  const unsigned short* xb = g.xb;
  for (int base = e0; base < e1; base += 64) {
    int m = e1 - base;
    if (m > 64) m = 64;
    int se = 0;
    float sc = 0.f;
    if (lane < m) {
      se = g.csr[base + lane];   // coalesced
      sc = g.rso[se];            // one 4B gather per edge, amortized over chunk
    }
    int j = 0;
    for (; j + 4 <= m; j += 4) {
      int s0 = __shfl(se, j), s1 = __shfl(se, j + 1);
      int s2 = __shfl(se, j + 2), s3 = __shfl(se, j + 3);
      float c0 = __shfl(sc, j), c1 = __shfl(sc, j + 1);
      float c2 = __shfl(sc, j + 2), c3 = __shfl(sc, j + 3);
      unsigned v0 = *(const unsigned*)&xb[(size_t)s0 * 128 + lane * 2];
      unsigned v1 = *(const unsigned*)&xb[(size_t)s1 * 128 + lane * 2];
      unsigned v2 = *(const unsigned*)&xb[(size_t)s2 * 128 + lane * 2];
      unsigned v3 = *(const unsigned*)&xb[(size_t)s3 * 128 + lane * 2];
      ax = fmaf(__uint_as_float(v0 << 16), c0, ax);
      ay = fmaf(__uint_as_float(v0 & 0xffff0000u), c0, ay);
      ax = fmaf(__uint_as_float(v1 << 16), c1, ax);
      ay = fmaf(__uint_as_float(v1 & 0xffff0000u), c1, ay);
      ax = fmaf(__uint_as_float(v2 << 16), c2, ax);
      ay = fmaf(__uint_as_float(v2 & 0xffff0000u), c2, ay);
      ax = fmaf(__uint_as_float(v3 << 16), c3, ax);
      ay = fmaf(__uint_as_float(v3 & 0xffff0000u), c3, ay);
    }
    for (; j < m; ++j) {
      int s0 = __shfl(se, j);
      float c0 = __shfl(sc, j);
      unsigned v0 = *(const unsigned*)&xb[(size_t)s0 * 128 + lane * 2];
      ax = fmaf(__uint_as_float(v0 << 16), c0, ax);
      ay = fmaf(__uint_as_float(v0 & 0xffff0000u), c0, ay);
    }
  }
  float si = g.rsi[wid];
  unsigned o = ((unsigned)f2bf(ay * si) << 16) | (unsigned)f2bf(ax * si);
  *(unsigned*)&g.out[(size_t)wid * g.stride + g.ooff + lane * 2] = o;
}

// ---------------- layer GEMM: H = lrelu(scale*(A @ [W0;W1] + b0 + b1)) ----------------
// A: M x (KCH*128) bf16. W0/W1: 128x128 f32. H: M x 128 f32 (+ optional bf16 copy).

template <int KCH>
__global__ __launch_bounds__(256) void k_lgemm(const unsigned short* __restrict__ A,
    const float* __restrict__ W0, const float* __restrict__ W1,
    const float* __restrict__ b0, const float* __restrict__ b1,
    float scale, float* __restrict__ H, unsigned short* __restrict__ Hb, int M) {
  __shared__ float Wsh[128 * 64];
  __shared__ float Ash[64 * 128];
  const int ASTRIDE = KCH * 128;
  int t = threadIdx.x;
  int m0 = blockIdx.x * 64;
  int n0 = blockIdx.y * 64;
  int tx = t & 15, ty = t >> 4, sw = ty & 3;
  float acc[4][4] = {};
  for (int c = 0; c < KCH; ++c) {
    const float* Wc = (c == 0) ? W0 : W1;
    for (int i = t; i < 128 * 16; i += 256) {
      int r = i >> 4, c4 = i & 15;
      *(float4*)&Wsh[r * 64 + c4 * 4] = *(const float4*)&Wc[r * 128 + n0 + c4 * 4];
    }
    for (int i = t; i < 64 * 32; i += 256) {
      int r = i >> 5, g = i & 31;
      int row = m0 + r;
      float4 v = {0.f, 0.f, 0.f, 0.f};
      if (row < M) {
        ushort4 u = *(const ushort4*)&A[(size_t)row * ASTRIDE + c * 128 + g * 4];
        v.x = bf2f(u.x); v.y = bf2f(u.y); v.z = bf2f(u.z); v.w = bf2f(u.w);
      }
      int gs = g ^ ((r >> 2) & 3);
      *(float4*)&Ash[r * 128 + gs * 4] = v;
    }
    __syncthreads();
#pragma unroll 8
    for (int k = 0; k < 128; ++k) {
      float4 w = *(const float4*)&Wsh[k * 64 + tx * 4];
      int kidx = (((k >> 2) ^ sw) << 2) | (k & 3);
#pragma unroll
      for (int i = 0; i < 4; ++i) {
        float av = Ash[(ty * 4 + i) * 128 + kidx];
        acc[i][0] += av * w.x;
        acc[i][1] += av * w.y;
        acc[i][2] += av * w.z;
        acc[i][3] += av * w.w;
      }
    }
    __syncthreads();
  }
  float4 bv = *(const float4*)&b0[n0 + tx * 4];
  if (b1) {
    float4 b2v = *(const float4*)&b1[n0 + tx * 4];
    bv.x += b2v.x; bv.y += b2v.y; bv.z += b2v.z; bv.w += b2v.w;
  }
#pragma unroll
  for (int i = 0; i < 4; ++i) {
    int row = m0 + ty * 4 + i;
    if (row < M) {
      float4 o;
      o.x = scale * (acc[i][0] + bv.x);
      o.y = scale * (acc[i][1] + bv.y);
      o.z = scale * (acc[i][2] + bv.z);
      o.w = scale * (acc[i][3] + bv.w);
      o.x = o.x >= 0.f ? o.x : LRELU * o.x;
      o.y = o.y >= 0.f ? o.y : LRELU * o.y;
      o.z = o.z >= 0.f ? o.z : LRELU * o.z;
      o.w = o.w >= 0.f ? o.w : LRELU * o.w;
      *(float4*)&H[(size_t)row * 128 + n0 + tx * 4] = o;
      if (Hb) {
        ushort4 ob = {f2bf(o.x), f2bf(o.y), f2bf(o.z), f2bf(o.w)};
        *(ushort4*)&Hb[(size_t)row * 128 + n0 + tx * 4] = ob;
      }
    }
  }
}

// ---------------- projection GEMM (f32 A, K=128, N=64) ----------------

__global__ __launch_bounds__(256) void k_pgemm(const float* __restrict__ A,
    const float* __restrict__ W, const float* __restrict__ bias,
    float* __restrict__ C, int M) {
  __shared__ float Wsh[128 * 64];
  __shared__ float Ash[64 * 128];
  int t = threadIdx.x;
  int m0 = blockIdx.x * 64;
  for (int i = t; i < 128 * 16; i += 256) {
    int r = i >> 4, c4 = i & 15;
    *(float4*)&Wsh[r * 64 + c4 * 4] = *(const float4*)&W[r * 64 + c4 * 4];
  }
  for (int i = t; i < 64 * 32; i += 256) {
    int r = i >> 5, g = i & 31;
    int row = m0 + r;
    float4 v = {0.f, 0.f, 0.f, 0.f};
    if (row < M) v = *(const float4*)&A[(size_t)row * 128 + g * 4];
    int gs = g ^ ((r >> 2) & 3);
    *(float4*)&Ash[r * 128 + gs * 4] = v;
  }
  __syncthreads();
  int tx = t & 15, ty = t >> 4, sw = ty & 3;
  float acc[4][4] = {};
#pragma unroll 8
  for (int k = 0; k < 128; ++k) {
    float4 w = *(const float4*)&Wsh[k * 64 + tx * 4];
    int kidx = (((k >> 2) ^ sw) << 2) | (k & 3);
#pragma unroll
    for (int i = 0; i < 4; ++i) {
      float av = Ash[(ty * 4 + i) * 128 + kidx];
      acc[i][0] += av * w.x;
      acc[i][1] += av * w.y;
      acc[i][2] += av * w.z;
      acc[i][3] += av * w.w;
    }
  }
  float4 bv = *(const float4*)&bias[tx * 4];
#pragma unroll
  for (int i = 0; i < 4; ++i) {
    int row = m0 + ty * 4 + i;
    if (row < M) {
      float4 o = {acc[i][0] + bv.x, acc[i][1] + bv.y, acc[i][2] + bv.z, acc[i][3] + bv.w};
      *(float4*)&C[(size_t)row * 64 + tx * 4] = o;
    }
  }
}

// ---------------- host ----------------

extern "C" void kernel_launch(void* const* d_in, const int* in_sizes, int n_in,
                              void* d_out, int out_size, void* d_ws, size_t ws_size,
                              hipStream_t stream) {
  const float* xu = (const float*)d_in[0];
  const float* xn = (const float*)d_in[1];
  const float* xs = (const float*)d_in[2];
  const float* W1 = (const float*)d_in[3];
  const float* b1 = (const float*)d_in[4];
  const float* W2 = (const float*)d_in[5];
  const float* b2 = (const float*)d_in[6];
  const float* Wu = (const float*)d_in[7];
  const float* bu = (const float*)d_in[8];
  const float* Wn = (const float*)d_in[9];
  const float* bn = (const float*)d_in[10];
  const float* Wsrc = (const float*)d_in[11];
  const float* bsrc = (const float*)d_in[12];
  const int* SRC[5] = {(const int*)d_in[13], (const int*)d_in[15], (const int*)d_in[17],
                       (const int*)d_in[19], (const int*)d_in[21]};
  const int* DST[5] = {(const int*)d_in[14], (const int*)d_in[16], (const int*)d_in[18],
                       (const int*)d_in[20], (const int*)d_in[22]};

  // ---- workspace layout (~64 MB) ----
  int* ws_i = (int*)d_ws;
  int* cnt = ws_i;                         // 284000
  int* cur = ws_i + 284000;                // 142000 (contiguous with cnt: one memset)
  int* rp = ws_i + 426000;                 // 142008
  int* csr = ws_i + 568008;                // 1400000
  int* csums = ws_i + 1968008;             // 320
  float* rs = (float*)(ws_i + 1968328);    // 284000
  unsigned short* aggU = (unsigned short*)(rs + 284000);  // 50000*256
  unsigned short* aggN = aggU + 12800000;                 // 20000*256
  unsigned short* aggS = aggN + 5120000;                  // 2000*128
  unsigned short* xbU = aggS + 256000;                    // 50000*128
  unsigned short* xbN = xbU + 6400000;                    // 20000*128
  unsigned short* xbS = xbN + 2560000;                    // 2000*128

  // ---- d_out layout ----
  float* outf = (float*)d_out;
  float* ou = outf;                 // 50000*64
  float* on = outf + 3200000;       // 20000*64
  float* osrc = outf + 4480000;     // 2000*64
  float* hu = outf + 4608000;       // 50000*128
  float* hn = outf + 11008000;      // 20000*128
  float* hs = outf + 13568000;      // 2000*128

  // ---- graph build ----
  hipMemsetAsync(cnt, 0, (size_t)426000 * 4, stream);
  EdgeArgs ea;
  for (int r = 0; r < 5; ++r)
    ea.rel[r] = {SRC[r], DST[r], cnt + DOUT_OFF[r], cnt + DIN_OFF[r], REL_E[r]};
  k_count<<<5470, 256, 0, stream>>>(ea);
  k_rs<<<1110, 256, 0, stream>>>(cnt, rs, 284000);
  ScanArgs sa;
  for (int r = 0; r < 5; ++r) {
    sa.cnt[r] = cnt + DIN_OFF[r];
    sa.rp[r] = rp + RP_OFF[r];
    sa.n[r] = REL_ND[r];
  }
  sa.csums = csums;
  k_scan1<<<140, 256, 0, stream>>>(sa);
  k_scan2<<<1, 64, 0, stream>>>(sa);
  k_scan3<<<140, 256, 0, stream>>>(sa);
  FillArgs fa;
  for (int r = 0; r < 5; ++r)
    fa.rel[r] = {SRC[r], DST[r], rp + RP_OFF[r], cur + CUR_OFF[r], csr + CSR_OFF[r], REL_E[r]};
  k_fill<<<5470, 256, 0, stream>>>(fa);

  // ---- bf16 feature tables for layer-1 gather ----
  k_f2bf<<<(kNU * 32 + 255) / 256, 256, 0, stream>>>(xu, xbU, kNU * 32);
  k_f2bf<<<(kNN * 32 + 255) / 256, 256, 0, stream>>>(xn, xbN, kNN * 32);
  k_f2bf<<<(kNS * 32 + 255) / 256, 256, 0, stream>>>(xs, xbS, kNS * 32);

  // ---- one hetero layer: gather (bf16 in/out) per relation, then fused GEMMs ----
  auto layer = [&](const unsigned short* inU, const unsigned short* inN,
                   const unsigned short* inS, const float* Wl, const float* bl,
                   bool writeHb) {
    const unsigned short* XIN[5] = {inU, inU, inN, inS, inN};
    unsigned short* OUT[5] = {aggU, aggN, aggU, aggN, aggS};
    const int OSTR[5] = {256, 256, 256, 256, 128};
    const int OOFF[5] = {0, 0, 128, 128, 0};
    GArgs ga;
    for (int r = 0; r < 5; ++r)
      ga.rel[r] = {rp + RP_OFF[r], csr + CSR_OFF[r], XIN[r], rs + DOUT_OFF[r],
                   rs + DIN_OFF[r], OUT[r], OSTR[r], OOFF[r], REL_ND[r]};
    k_gather<<<35500, 256, 0, stream>>>(ga);
    k_lgemm<2><<<dim3(782, 2), 256, 0, stream>>>(aggU, Wl + 0 * 16384, Wl + 2 * 16384,
        bl + 0 * 128, bl + 2 * 128, 0.5f, hu, writeHb ? xbU : nullptr, kNU);
    k_lgemm<2><<<dim3(313, 2), 256, 0, stream>>>(aggN, Wl + 1 * 16384, Wl + 3 * 16384,
        bl + 1 * 128, bl + 3 * 128, 0.5f, hn, writeHb ? xbN : nullptr, kNN);
    k_lgemm<1><<<dim3(32, 2), 256, 0, stream>>>(aggS, Wl + 4 * 16384, nullptr,
        bl + 4 * 128, nullptr, 1.0f, hs, writeHb ? xbS : nullptr, kNS);
  };

  // layer 1: x -> h1 (f32 in d_out slots, bf16 copy into xb* for layer-2 gather)
  layer(xbU, xbN, xbS, W1, b1, true);
  // layer 2: h1 -> h2
  layer(xbU, xbN, xbS, W2, b2, false);

  // ---- output projections ----
  k_pgemm<<<782, 256, 0, stream>>>(hu, Wu, bu, ou, kNU);
  k_pgemm<<<313, 256, 0, stream>>>(hn, Wn, bn, on, kNN);
  k_pgemm<<<32, 256, 0, stream>>>(hs, Wsrc, bsrc, osrc, kNS);
}

// Round 4
// 526.910 us; speedup vs baseline: 2.2500x; 1.2406x over previous
//
#include <hip/hip_runtime.h>

#define LRELU 0.01f

// ---------------- problem constants ----------------
// relations: 0 follows U->U, 1 posts U->N, 2 posted_by N->U, 3 publishes S->N, 4 published_by N->S
static const int kNU = 50000, kNN = 20000, kNS = 2000;
static const int REL_E[5]  = {500000, 300000, 300000, 150000, 150000};
static const int REL_ND[5] = {50000, 20000, 50000, 20000, 2000};
// offsets into cnt/rs arrays (dout and din regions share one buffer)
static const int DOUT_OFF[5] = {0, 100000, 170000, 240000, 262000};
static const int DIN_OFF[5]  = {50000, 150000, 190000, 242000, 282000};
static const int RP_OFF[5]   = {0, 50001, 70002, 120003, 140004};
static const int CSR_OFF[5]  = {0, 500000, 800000, 1100000, 1250000};

using bf16x8 = __attribute__((ext_vector_type(8))) short;
using f32x4  = __attribute__((ext_vector_type(4))) float;

__device__ __forceinline__ float bf2f(unsigned short u) {
  return __uint_as_float(((unsigned)u) << 16);
}
__device__ __forceinline__ unsigned short f2bf(float f) {  // RNE
  unsigned u = __float_as_uint(f);
  u += 0x7FFFu + ((u >> 16) & 1u);
  return (unsigned short)(u >> 16);
}

// ---------------- graph build ----------------
// pass 1: dout atomic count + din atomic count (returned value = CSR slot, saved)

struct RelB1 { const int* src; const int* dst; int* dout; int* din; int* pos; int E; };
struct B1Args { RelB1 rel[5]; };

__global__ __launch_bounds__(256) void k_build1(B1Args a) {
  constexpr int ESTART[6] = {0, 1954, 3126, 4298, 4884, 5470};
  int bx = blockIdx.x, r = 0;
  while (bx >= ESTART[r + 1]) ++r;
  RelB1 e = a.rel[r];
  int i = (bx - ESTART[r]) * 256 + threadIdx.x;
  if (i < e.E) {
    atomicAdd(&e.dout[e.src[i]], 1);
    int p = atomicAdd(&e.din[e.dst[i]], 1);
    e.pos[i] = p;
  }
}

// pass 2: atomic-free scatter
struct RelB2 { const int* src; const int* dst; const int* rp; const int* pos; int* csr; int E; };
struct B2Args { RelB2 rel[5]; };

__global__ __launch_bounds__(256) void k_build2(B2Args a) {
  constexpr int ESTART[6] = {0, 1954, 3126, 4298, 4884, 5470};
  int bx = blockIdx.x, r = 0;
  while (bx >= ESTART[r + 1]) ++r;
  RelB2 f = a.rel[r];
  int i = (bx - ESTART[r]) * 256 + threadIdx.x;
  if (i < f.E) {
    int d = f.dst[i];
    f.csr[f.rp[d] + f.pos[i]] = f.src[i];
  }
}

__global__ __launch_bounds__(256) void k_rs(const int* __restrict__ cnt,
                                            float* __restrict__ rs, int n) {
  int i = blockIdx.x * 256 + threadIdx.x;
  if (i < n) {
    int c = cnt[i];
    rs[i] = rsqrtf((float)(c > 1 ? c : 1));
  }
}

struct ScanArgs { const int* cnt[5]; int* rp[5]; int n[5]; int* csums; };

__global__ __launch_bounds__(256) void k_scan1(ScanArgs a) {
  constexpr int CSTART[6] = {0, 49, 69, 118, 138, 140};
  int bx = blockIdx.x, r = 0;
  while (bx >= CSTART[r + 1]) ++r;
  int chunk = bx - CSTART[r];
  int n = a.n[r];
  int base = chunk * 1024;
  const int* cnt = a.cnt[r];
  int t = threadIdx.x;
  int s = 0;
#pragma unroll
  for (int j = 0; j < 4; ++j) {
    int idx = base + j * 256 + t;
    if (idx < n) s += cnt[idx];
  }
  __shared__ int sd[256];
  sd[t] = s;
  __syncthreads();
  for (int off = 128; off > 0; off >>= 1) {
    if (t < off) sd[t] += sd[t + off];
    __syncthreads();
  }
  if (t == 0) a.csums[r * 64 + chunk] = sd[0];
}

__global__ __launch_bounds__(64) void k_scan2(ScanArgs a) {
  constexpr int NCH[5] = {49, 20, 49, 20, 2};
  int r = threadIdx.x;
  if (r < 5) {
    int run = 0;
    for (int i = 0; i < NCH[r]; ++i) {
      int v = a.csums[r * 64 + i];
      a.csums[r * 64 + i] = run;
      run += v;
    }
    a.rp[r][a.n[r]] = run;
  }
}

__global__ __launch_bounds__(256) void k_scan3(ScanArgs a) {
  constexpr int CSTART[6] = {0, 49, 69, 118, 138, 140};
  int bx = blockIdx.x, r = 0;
  while (bx >= CSTART[r + 1]) ++r;
  int chunk = bx - CSTART[r];
  int n = a.n[r];
  int base = chunk * 1024;
  const int* cnt = a.cnt[r];
  int* rp = a.rp[r];
  int t = threadIdx.x;
  int idx0 = base + t * 4;
  int v[4];
#pragma unroll
  for (int j = 0; j < 4; ++j) v[j] = (idx0 + j < n) ? cnt[idx0 + j] : 0;
  int tsum = v[0] + v[1] + v[2] + v[3];
  __shared__ int sd[256];
  sd[t] = tsum;
  __syncthreads();
  for (int s = 1; s < 256; s <<= 1) {
    int add = (t >= s) ? sd[t - s] : 0;
    __syncthreads();
    sd[t] += add;
    __syncthreads();
  }
  int off = a.csums[r * 64 + chunk] + sd[t] - tsum;
#pragma unroll
  for (int j = 0; j < 4; ++j) {
    if (idx0 + j < n) rp[idx0 + j] = off;
    off += v[j];
  }
}

// ---------------- f32 -> bf16 convert ----------------

__global__ __launch_bounds__(256) void k_f2bf(const float* __restrict__ in,
    unsigned short* __restrict__ out, int n4) {
  int i = blockIdx.x * 256 + threadIdx.x;
  if (i >= n4) return;
  float4 v = ((const float4*)in)[i];
  ushort4 o = {f2bf(v.x), f2bf(v.y), f2bf(v.z), f2bf(v.w)};
  ((ushort4*)out)[i] = o;
}

// ---------------- weight prep: transpose + hi/lo bf16 split ----------------

struct PrepJob { const float* W0; const float* W128; unsigned short* hi;
                 unsigned short* lo; int NOUT; int lgK; int bstart; };
struct PrepArgs { PrepJob j[9]; };

__global__ __launch_bounds__(256) void k_wprep(PrepArgs a) {
  int bx = blockIdx.x, ji = 0;
  while (ji < 8 && bx >= a.j[ji + 1].bstart) ++ji;
  PrepJob p = a.j[ji];
  int idx = (bx - p.bstart) * 256 + threadIdx.x;
  int K = 1 << p.lgK;
  int n = idx >> p.lgK, k = idx & (K - 1);
  if (n >= p.NOUT) return;
  float w = (k < 128) ? p.W0[k * p.NOUT + n] : p.W128[(k - 128) * p.NOUT + n];
  unsigned short h = f2bf(w);
  float res = w - bf2f(h);
  p.hi[n * K + k] = h;
  p.lo[n * K + k] = f2bf(res);
}

// ---------------- aggregate (gather bf16 features, write bf16) ----------------

struct RelG {
  const int* rp; const int* csr; const unsigned short* xb;
  const float* rso; const float* rsi;
  unsigned short* out; int stride; int ooff; int nd;
};
struct GArgs { RelG rel[5]; };

__global__ __launch_bounds__(256) void k_gather(GArgs a) {
  constexpr int GSTART[6] = {0, 12500, 17500, 30000, 35000, 35500};
  int bx = blockIdx.x, r = 0;
  while (bx >= GSTART[r + 1]) ++r;
  RelG g = a.rel[r];
  int wid = (bx - GSTART[r]) * 4 + (threadIdx.x >> 6);
  if (wid >= g.nd) return;
  int lane = threadIdx.x & 63;
  int e0 = g.rp[wid], e1 = g.rp[wid + 1];
  float ax = 0.f, ay = 0.f;
  const unsigned short* xb = g.xb;
  for (int base = e0; base < e1; base += 64) {
    int m = e1 - base;
    if (m > 64) m = 64;
    int se = 0;
    float sc = 0.f;
    if (lane < m) {
      se = g.csr[base + lane];   // coalesced
      sc = g.rso[se];
    }
    int j = 0;
    for (; j + 8 <= m; j += 8) {
      int s0 = __shfl(se, j), s1 = __shfl(se, j + 1);
      int s2 = __shfl(se, j + 2), s3 = __shfl(se, j + 3);
      int s4 = __shfl(se, j + 4), s5 = __shfl(se, j + 5);
      int s6 = __shfl(se, j + 6), s7 = __shfl(se, j + 7);
      float c0 = __shfl(sc, j), c1 = __shfl(sc, j + 1);
      float c2 = __shfl(sc, j + 2), c3 = __shfl(sc, j + 3);
      float c4 = __shfl(sc, j + 4), c5 = __shfl(sc, j + 5);
      float c6 = __shfl(sc, j + 6), c7 = __shfl(sc, j + 7);
      unsigned v0 = *(const unsigned*)&xb[(size_t)s0 * 128 + lane * 2];
      unsigned v1 = *(const unsigned*)&xb[(size_t)s1 * 128 + lane * 2];
      unsigned v2 = *(const unsigned*)&xb[(size_t)s2 * 128 + lane * 2];
      unsigned v3 = *(const unsigned*)&xb[(size_t)s3 * 128 + lane * 2];
      unsigned v4 = *(const unsigned*)&xb[(size_t)s4 * 128 + lane * 2];
      unsigned v5 = *(const unsigned*)&xb[(size_t)s5 * 128 + lane * 2];
      unsigned v6 = *(const unsigned*)&xb[(size_t)s6 * 128 + lane * 2];
      unsigned v7 = *(const unsigned*)&xb[(size_t)s7 * 128 + lane * 2];
      ax = fmaf(__uint_as_float(v0 << 16), c0, ax);
      ay = fmaf(__uint_as_float(v0 & 0xffff0000u), c0, ay);
      ax = fmaf(__uint_as_float(v1 << 16), c1, ax);
      ay = fmaf(__uint_as_float(v1 & 0xffff0000u), c1, ay);
      ax = fmaf(__uint_as_float(v2 << 16), c2, ax);
      ay = fmaf(__uint_as_float(v2 & 0xffff0000u), c2, ay);
      ax = fmaf(__uint_as_float(v3 << 16), c3, ax);
      ay = fmaf(__uint_as_float(v3 & 0xffff0000u), c3, ay);
      ax = fmaf(__uint_as_float(v4 << 16), c4, ax);
      ay = fmaf(__uint_as_float(v4 & 0xffff0000u), c4, ay);
      ax = fmaf(__uint_as_float(v5 << 16), c5, ax);
      ay = fmaf(__uint_as_float(v5 & 0xffff0000u), c5, ay);
      ax = fmaf(__uint_as_float(v6 << 16), c6, ax);
      ay = fmaf(__uint_as_float(v6 & 0xffff0000u), c6, ay);
      ax = fmaf(__uint_as_float(v7 << 16), c7, ax);
      ay = fmaf(__uint_as_float(v7 & 0xffff0000u), c7, ay);
    }
    for (; j < m; ++j) {
      int s0 = __shfl(se, j);
      float c0 = __shfl(sc, j);
      unsigned v0 = *(const unsigned*)&xb[(size_t)s0 * 128 + lane * 2];
      ax = fmaf(__uint_as_float(v0 << 16), c0, ax);
      ay = fmaf(__uint_as_float(v0 & 0xffff0000u), c0, ay);
    }
  }
  float si = g.rsi[wid];
  unsigned o = ((unsigned)f2bf(ay * si) << 16) | (unsigned)f2bf(ax * si);
  *(unsigned*)&g.out[(size_t)wid * g.stride + g.ooff + lane * 2] = o;
}

// ---------------- MFMA GEMM ----------------
// H[M x NW*64] = epi(A[M x KCH*128](bf16) @ (Whi+Wlo)[KCH*128 x NW*64])
// W stored transposed [n][k] bf16, hi/lo planes. Block = 4 waves, 64 rows.
// Wave w: all 64 rows x cols [w*NW*16, (w+1)*NW*16). No LDS; fragment loads
// are 16B contiguous, lanes {l,l+16,l+32,l+48} cover 64B lines.

template <int KCH, int NW>
__global__ __launch_bounds__(256) void k_mgemm(
    const unsigned short* __restrict__ A,
    const unsigned short* __restrict__ Whi, const unsigned short* __restrict__ Wlo,
    const float* __restrict__ b0, const float* __restrict__ b1,
    float scale, int lrelu_on,
    float* __restrict__ H, int ldh, unsigned short* __restrict__ Hb, int M) {
  constexpr int KP = KCH * 128;
  int t = threadIdx.x;
  int w = t >> 6, l = t & 63;
  int lo16 = l & 15, hi4 = l >> 4;
  int m0 = blockIdx.x * 64;
  f32x4 acc[4][NW] = {};
  for (int s = 0; s < KP / 32; ++s) {
    int kbase = s * 32 + hi4 * 8;
    bf16x8 af[4];
#pragma unroll
    for (int mf = 0; mf < 4; ++mf) {
      int row = m0 + mf * 16 + lo16;
      row = row < M ? row : M - 1;  // clamp; OOB rows never stored
      af[mf] = *(const bf16x8*)&A[(size_t)row * KP + kbase];
    }
#pragma unroll
    for (int nf = 0; nf < NW; ++nf) {
      int n = (w * NW + nf) * 16 + lo16;
      bf16x8 bh = *(const bf16x8*)&Whi[(size_t)n * KP + kbase];
      bf16x8 bl = *(const bf16x8*)&Wlo[(size_t)n * KP + kbase];
#pragma unroll
      for (int mf = 0; mf < 4; ++mf) {
        acc[mf][nf] = __builtin_amdgcn_mfma_f32_16x16x32_bf16(af[mf], bh, acc[mf][nf], 0, 0, 0);
        acc[mf][nf] = __builtin_amdgcn_mfma_f32_16x16x32_bf16(af[mf], bl, acc[mf][nf], 0, 0, 0);
      }
    }
  }
#pragma unroll
  for (int nf = 0; nf < NW; ++nf) {
    int col = (w * NW + nf) * 16 + lo16;
    float bs = b0[col];
    if (b1) bs += b1[col];
#pragma unroll
    for (int mf = 0; mf < 4; ++mf) {
#pragma unroll
      for (int r = 0; r < 4; ++r) {
        int row = m0 + mf * 16 + hi4 * 4 + r;
        if (row < M) {
          float o = scale * (acc[mf][nf][r] + bs);
          if (lrelu_on) o = o >= 0.f ? o : LRELU * o;
          H[(size_t)row * ldh + col] = o;
          if (Hb) Hb[(size_t)row * ldh + col] = f2bf(o);
        }
      }
    }
  }
}

// ---------------- host ----------------

extern "C" void kernel_launch(void* const* d_in, const int* in_sizes, int n_in,
                              void* d_out, int out_size, void* d_ws, size_t ws_size,
                              hipStream_t stream) {
  const float* xu = (const float*)d_in[0];
  const float* xn = (const float*)d_in[1];
  const float* xs = (const float*)d_in[2];
  const float* W1 = (const float*)d_in[3];
  const float* b1 = (const float*)d_in[4];
  const float* W2 = (const float*)d_in[5];
  const float* b2 = (const float*)d_in[6];
  const float* Wu = (const float*)d_in[7];
  const float* bu = (const float*)d_in[8];
  const float* Wn = (const float*)d_in[9];
  const float* bn = (const float*)d_in[10];
  const float* Wsrc = (const float*)d_in[11];
  const float* bsrc = (const float*)d_in[12];
  const int* SRC[5] = {(const int*)d_in[13], (const int*)d_in[15], (const int*)d_in[17],
                       (const int*)d_in[19], (const int*)d_in[21]};
  const int* DST[5] = {(const int*)d_in[14], (const int*)d_in[16], (const int*)d_in[18],
                       (const int*)d_in[20], (const int*)d_in[22]};

  // ---- workspace layout (~69.6 MB) ----
  int* ws_i = (int*)d_ws;
  int* cnt = ws_i;                          // 284000 (dout + din regions)
  int* rp = ws_i + 284000;                  // 142008
  int* csr = ws_i + 426008;                 // 1400000
  int* pos = ws_i + 1826008;                // 1400000
  int* csums = ws_i + 3226008;              // 320
  float* rs = (float*)(ws_i + 3226328);     // 284000
  unsigned short* wt = (unsigned short*)(rs + 284000);    // 376832
  unsigned short* aggU = wt + 376832;       // 50000*256
  unsigned short* aggN = aggU + 12800000;   // 20000*256
  unsigned short* aggS = aggN + 5120000;    // 2000*128
  unsigned short* xbU = aggS + 256000;      // 50000*128
  unsigned short* xbN = xbU + 6400000;      // 20000*128
  unsigned short* xbS = xbN + 2560000;      // 2000*128

  // wt sub-offsets (hi, lo consecutive per job)
  unsigned short* L1U_h = wt, * L1U_l = wt + 32768;
  unsigned short* L1N_h = wt + 65536, * L1N_l = wt + 98304;
  unsigned short* L1S_h = wt + 131072, * L1S_l = wt + 147456;
  unsigned short* L2U_h = wt + 163840, * L2U_l = wt + 196608;
  unsigned short* L2N_h = wt + 229376, * L2N_l = wt + 262144;
  unsigned short* L2S_h = wt + 294912, * L2S_l = wt + 311296;
  unsigned short* PU_h = wt + 327680, * PU_l = wt + 335872;
  unsigned short* PN_h = wt + 344064, * PN_l = wt + 352256;
  unsigned short* PS_h = wt + 360448, * PS_l = wt + 368640;

  // ---- d_out layout ----
  float* outf = (float*)d_out;
  float* ou = outf;                 // 50000*64
  float* on = outf + 3200000;       // 20000*64
  float* osrc = outf + 4480000;     // 2000*64
  float* hu = outf + 4608000;       // 50000*128
  float* hn = outf + 11008000;      // 20000*128
  float* hs = outf + 13568000;      // 2000*128

  // ---- graph build ----
  hipMemsetAsync(cnt, 0, (size_t)284000 * 4, stream);
  B1Args ba;
  for (int r = 0; r < 5; ++r)
    ba.rel[r] = {SRC[r], DST[r], cnt + DOUT_OFF[r], cnt + DIN_OFF[r],
                 pos + CSR_OFF[r], REL_E[r]};
  k_build1<<<5470, 256, 0, stream>>>(ba);
  k_rs<<<1110, 256, 0, stream>>>(cnt, rs, 284000);
  ScanArgs sa;
  for (int r = 0; r < 5; ++r) {
    sa.cnt[r] = cnt + DIN_OFF[r];
    sa.rp[r] = rp + RP_OFF[r];
    sa.n[r] = REL_ND[r];
  }
  sa.csums = csums;
  k_scan1<<<140, 256, 0, stream>>>(sa);
  k_scan2<<<1, 64, 0, stream>>>(sa);
  k_scan3<<<140, 256, 0, stream>>>(sa);
  B2Args b2a;
  for (int r = 0; r < 5; ++r)
    b2a.rel[r] = {SRC[r], DST[r], rp + RP_OFF[r], pos + CSR_OFF[r],
                  csr + CSR_OFF[r], REL_E[r]};
  k_build2<<<5470, 256, 0, stream>>>(b2a);

  // ---- weight prep (transpose + hi/lo split) ----
  PrepArgs pa;
  pa.j[0] = {W1, W1 + 2 * 16384, L1U_h, L1U_l, 128, 8, 0};
  pa.j[1] = {W1 + 16384, W1 + 3 * 16384, L1N_h, L1N_l, 128, 8, 128};
  pa.j[2] = {W1 + 4 * 16384, nullptr, L1S_h, L1S_l, 128, 7, 256};
  pa.j[3] = {W2, W2 + 2 * 16384, L2U_h, L2U_l, 128, 8, 320};
  pa.j[4] = {W2 + 16384, W2 + 3 * 16384, L2N_h, L2N_l, 128, 8, 448};
  pa.j[5] = {W2 + 4 * 16384, nullptr, L2S_h, L2S_l, 128, 7, 576};
  pa.j[6] = {Wu, nullptr, PU_h, PU_l, 64, 7, 640};
  pa.j[7] = {Wn, nullptr, PN_h, PN_l, 64, 7, 672};
  pa.j[8] = {Wsrc, nullptr, PS_h, PS_l, 64, 7, 704};
  k_wprep<<<736, 256, 0, stream>>>(pa);

  // ---- bf16 feature tables for layer-1 gather ----
  k_f2bf<<<(kNU * 32 + 255) / 256, 256, 0, stream>>>(xu, xbU, kNU * 32);
  k_f2bf<<<(kNN * 32 + 255) / 256, 256, 0, stream>>>(xn, xbN, kNN * 32);
  k_f2bf<<<(kNS * 32 + 255) / 256, 256, 0, stream>>>(xs, xbS, kNS * 32);

  // ---- hetero layer: gather per relation, then MFMA GEMMs ----
  auto layer = [&](const unsigned short* Uh, const unsigned short* Ul,
                   const unsigned short* Nh, const unsigned short* Nl,
                   const unsigned short* Sh, const unsigned short* Sl,
                   const float* bl) {
    const unsigned short* XIN[5] = {xbU, xbU, xbN, xbS, xbN};
    unsigned short* OUT[5] = {aggU, aggN, aggU, aggN, aggS};
    const int OSTR[5] = {256, 256, 256, 256, 128};
    const int OOFF[5] = {0, 0, 128, 128, 0};
    GArgs ga;
    for (int r = 0; r < 5; ++r)
      ga.rel[r] = {rp + RP_OFF[r], csr + CSR_OFF[r], XIN[r], rs + DOUT_OFF[r],
                   rs + DIN_OFF[r], OUT[r], OSTR[r], OOFF[r], REL_ND[r]};
    k_gather<<<35500, 256, 0, stream>>>(ga);
    k_mgemm<2, 2><<<782, 256, 0, stream>>>(aggU, Uh, Ul, bl, bl + 2 * 128,
        0.5f, 1, hu, 128, xbU, kNU);
    k_mgemm<2, 2><<<313, 256, 0, stream>>>(aggN, Nh, Nl, bl + 128, bl + 3 * 128,
        0.5f, 1, hn, 128, xbN, kNN);
    k_mgemm<1, 2><<<32, 256, 0, stream>>>(aggS, Sh, Sl, bl + 4 * 128, nullptr,
        1.0f, 1, hs, 128, xbS, kNS);
  };

  // layer 1: x -> h1 (f32 into d_out h-slots, bf16 into xb* for next stage)
  layer(L1U_h, L1U_l, L1N_h, L1N_l, L1S_h, L1S_l, b1);
  // layer 2: h1 -> h2 (gather reads xb*=h1 before lgemm overwrites with h2)
  layer(L2U_h, L2U_l, L2N_h, L2N_l, L2S_h, L2S_l, b2);

  // ---- output projections (read bf16 h2 from xb*) ----
  k_mgemm<1, 1><<<782, 256, 0, stream>>>(xbU, PU_h, PU_l, bu, nullptr,
      1.0f, 0, ou, 64, nullptr, kNU);
  k_mgemm<1, 1><<<313, 256, 0, stream>>>(xbN, PN_h, PN_l, bn, nullptr,
      1.0f, 0, on, 64, nullptr, kNN);
  k_mgemm<1, 1><<<32, 256, 0, stream>>>(xbS, PS_h, PS_l, bsrc, nullptr,
      1.0f, 0, osrc, 64, nullptr, kNS);
}

// Round 5
// 508.103 us; speedup vs baseline: 2.3333x; 1.0370x over previous
//
#include <hip/hip_runtime.h>

#define LRELU 0.01f

// ---------------- problem constants ----------------
// relations: 0 follows U->U, 1 posts U->N, 2 posted_by N->U, 3 publishes S->N, 4 published_by N->S
static const int kNU = 50000, kNN = 20000, kNS = 2000;
static const int REL_E[5]  = {500000, 300000, 300000, 150000, 150000};
static const int REL_ND[5] = {50000, 20000, 50000, 20000, 2000};
// offsets into cnt/rs arrays (dout and din regions share one buffer)
static const int DOUT_OFF[5] = {0, 100000, 170000, 240000, 262000};
static const int DIN_OFF[5]  = {50000, 150000, 190000, 242000, 282000};
static const int RP_OFF[5]   = {0, 50001, 70002, 120003, 140004};
static const int CSR_OFF[5]  = {0, 500000, 800000, 1100000, 1250000};

using bf16x8 = __attribute__((ext_vector_type(8))) short;
using u16x8  = __attribute__((ext_vector_type(8))) unsigned short;
using f32x4  = __attribute__((ext_vector_type(4))) float;

__device__ __forceinline__ float bf2f(unsigned short u) {
  return __uint_as_float(((unsigned)u) << 16);
}
__device__ __forceinline__ unsigned short f2bf(float f) {  // RNE
  unsigned u = __float_as_uint(f);
  u += 0x7FFFu + ((u >> 16) & 1u);
  return (unsigned short)(u >> 16);
}

// ---------------- graph build ----------------
// pass 1: dout atomic count (fire-and-forget) + din atomic count (return = CSR slot)

struct RelB1 { const int* src; const int* dst; int* dout; int* din; int* pos; int E; };
struct B1Args { RelB1 rel[5]; };

__global__ __launch_bounds__(256) void k_build1(B1Args a) {
  constexpr int ESTART[6] = {0, 1954, 3126, 4298, 4884, 5470};
  int bx = blockIdx.x, r = 0;
  while (bx >= ESTART[r + 1]) ++r;
  RelB1 e = a.rel[r];
  int i = (bx - ESTART[r]) * 256 + threadIdx.x;
  if (i < e.E) {
    atomicAdd(&e.dout[e.src[i]], 1);
    int p = atomicAdd(&e.din[e.dst[i]], 1);
    e.pos[i] = p;
  }
}

// pass 2: atomic-free scatter
struct RelB2 { const int* src; const int* dst; const int* rp; const int* pos; int* csr; int E; };
struct B2Args { RelB2 rel[5]; };

__global__ __launch_bounds__(256) void k_build2(B2Args a) {
  constexpr int ESTART[6] = {0, 1954, 3126, 4298, 4884, 5470};
  int bx = blockIdx.x, r = 0;
  while (bx >= ESTART[r + 1]) ++r;
  RelB2 f = a.rel[r];
  int i = (bx - ESTART[r]) * 256 + threadIdx.x;
  if (i < f.E) {
    int d = f.dst[i];
    f.csr[f.rp[d] + f.pos[i]] = f.src[i];
  }
}

__global__ __launch_bounds__(256) void k_rs(const int* __restrict__ cnt,
                                            float* __restrict__ rs, int n) {
  int i = blockIdx.x * 256 + threadIdx.x;
  if (i < n) {
    int c = cnt[i];
    rs[i] = rsqrtf((float)(c > 1 ? c : 1));
  }
}

struct ScanArgs { const int* cnt[5]; int* rp[5]; int n[5]; int* csums; };

__global__ __launch_bounds__(256) void k_scan1(ScanArgs a) {
  constexpr int CSTART[6] = {0, 49, 69, 118, 138, 140};
  int bx = blockIdx.x, r = 0;
  while (bx >= CSTART[r + 1]) ++r;
  int chunk = bx - CSTART[r];
  int n = a.n[r];
  int base = chunk * 1024;
  const int* cnt = a.cnt[r];
  int t = threadIdx.x;
  int s = 0;
#pragma unroll
  for (int j = 0; j < 4; ++j) {
    int idx = base + j * 256 + t;
    if (idx < n) s += cnt[idx];
  }
  __shared__ int sd[256];
  sd[t] = s;
  __syncthreads();
  for (int off = 128; off > 0; off >>= 1) {
    if (t < off) sd[t] += sd[t + off];
    __syncthreads();
  }
  if (t == 0) a.csums[r * 64 + chunk] = sd[0];
}

__global__ __launch_bounds__(64) void k_scan2(ScanArgs a) {
  constexpr int NCH[5] = {49, 20, 49, 20, 2};
  int r = threadIdx.x;
  if (r < 5) {
    int run = 0;
    for (int i = 0; i < NCH[r]; ++i) {
      int v = a.csums[r * 64 + i];
      a.csums[r * 64 + i] = run;
      run += v;
    }
    a.rp[r][a.n[r]] = run;
  }
}

__global__ __launch_bounds__(256) void k_scan3(ScanArgs a) {
  constexpr int CSTART[6] = {0, 49, 69, 118, 138, 140};
  int bx = blockIdx.x, r = 0;
  while (bx >= CSTART[r + 1]) ++r;
  int chunk = bx - CSTART[r];
  int n = a.n[r];
  int base = chunk * 1024;
  const int* cnt = a.cnt[r];
  int* rp = a.rp[r];
  int t = threadIdx.x;
  int idx0 = base + t * 4;
  int v[4];
#pragma unroll
  for (int j = 0; j < 4; ++j) v[j] = (idx0 + j < n) ? cnt[idx0 + j] : 0;
  int tsum = v[0] + v[1] + v[2] + v[3];
  __shared__ int sd[256];
  sd[t] = tsum;
  __syncthreads();
  for (int s = 1; s < 256; s <<= 1) {
    int add = (t >= s) ? sd[t - s] : 0;
    __syncthreads();
    sd[t] += add;
    __syncthreads();
  }
  int off = a.csums[r * 64 + chunk] + sd[t] - tsum;
#pragma unroll
  for (int j = 0; j < 4; ++j) {
    if (idx0 + j < n) rp[idx0 + j] = off;
    off += v[j];
  }
}

// ---------------- f32 -> bf16 convert (3 tables, one launch) ----------------

struct CvtJob { const float* in; unsigned short* out; int n4; int bstart; };
struct CvtArgs { CvtJob j[3]; };

__global__ __launch_bounds__(256) void k_f2bf3(CvtArgs a) {
  int bx = blockIdx.x, ji = 0;
  while (ji < 2 && bx >= a.j[ji + 1].bstart) ++ji;
  CvtJob p = a.j[ji];
  int i = (bx - p.bstart) * 256 + threadIdx.x;
  if (i >= p.n4) return;
  float4 v = ((const float4*)p.in)[i];
  ushort4 o = {f2bf(v.x), f2bf(v.y), f2bf(v.z), f2bf(v.w)};
  ((ushort4*)p.out)[i] = o;
}

// ---------------- weight prep: transpose + hi/lo bf16 split ----------------

struct PrepJob { const float* W0; const float* W128; unsigned short* hi;
                 unsigned short* lo; int NOUT; int lgK; int bstart; };
struct PrepArgs { PrepJob j[9]; };

__global__ __launch_bounds__(256) void k_wprep(PrepArgs a) {
  int bx = blockIdx.x, ji = 0;
  while (ji < 8 && bx >= a.j[ji + 1].bstart) ++ji;
  PrepJob p = a.j[ji];
  int idx = (bx - p.bstart) * 256 + threadIdx.x;
  int K = 1 << p.lgK;
  int n = idx >> p.lgK, k = idx & (K - 1);
  if (n >= p.NOUT) return;
  float w = (k < 128) ? p.W0[k * p.NOUT + n] : p.W128[(k - 128) * p.NOUT + n];
  unsigned short h = f2bf(w);
  float res = w - bf2f(h);
  p.hi[n * K + k] = h;
  p.lo[n * K + k] = f2bf(res);
}

// ---------------- aggregate: 16 lanes per dst row, 4 rows per wave ----------------
// Per edge: group-uniform broadcast loads of csr[e] and rso[s], then each lane
// reads bf16x8 (16B) of the src row -> 8 f32 accumulators. 4-unrolled for ILP.

struct RelG {
  const int* rp; const int* csr; const unsigned short* xb;
  const float* rso; const float* rsi;
  unsigned short* out; int stride; int ooff; int nd;
};
struct GArgs { RelG rel[5]; };

__global__ __launch_bounds__(256) void k_gather(GArgs a) {
  constexpr int GSTART[6] = {0, 3125, 4375, 7500, 8750, 8875};
  int bx = blockIdx.x, r = 0;
  while (bx >= GSTART[r + 1]) ++r;
  RelG g = a.rel[r];
  int t = threadIdx.x;
  int sub = t & 15;
  int wid = (bx - GSTART[r]) * 16 + (t >> 4);
  if (wid >= g.nd) return;
  int e0 = g.rp[wid], e1 = g.rp[wid + 1];
  const unsigned short* xb = g.xb;
  float acc[8] = {};
  int e = e0;
  for (; e + 4 <= e1; e += 4) {
    int s0 = g.csr[e], s1 = g.csr[e + 1], s2 = g.csr[e + 2], s3 = g.csr[e + 3];
    float c0 = g.rso[s0], c1 = g.rso[s1], c2 = g.rso[s2], c3 = g.rso[s3];
    bf16x8 v0 = *(const bf16x8*)&xb[(size_t)s0 * 128 + sub * 8];
    bf16x8 v1 = *(const bf16x8*)&xb[(size_t)s1 * 128 + sub * 8];
    bf16x8 v2 = *(const bf16x8*)&xb[(size_t)s2 * 128 + sub * 8];
    bf16x8 v3 = *(const bf16x8*)&xb[(size_t)s3 * 128 + sub * 8];
#pragma unroll
    for (int q = 0; q < 8; ++q)
      acc[q] = fmaf(__uint_as_float(((unsigned)(unsigned short)v0[q]) << 16), c0, acc[q]);
#pragma unroll
    for (int q = 0; q < 8; ++q)
      acc[q] = fmaf(__uint_as_float(((unsigned)(unsigned short)v1[q]) << 16), c1, acc[q]);
#pragma unroll
    for (int q = 0; q < 8; ++q)
      acc[q] = fmaf(__uint_as_float(((unsigned)(unsigned short)v2[q]) << 16), c2, acc[q]);
#pragma unroll
    for (int q = 0; q < 8; ++q)
      acc[q] = fmaf(__uint_as_float(((unsigned)(unsigned short)v3[q]) << 16), c3, acc[q]);
  }
  for (; e < e1; ++e) {
    int s0 = g.csr[e];
    float c0 = g.rso[s0];
    bf16x8 v0 = *(const bf16x8*)&xb[(size_t)s0 * 128 + sub * 8];
#pragma unroll
    for (int q = 0; q < 8; ++q)
      acc[q] = fmaf(__uint_as_float(((unsigned)(unsigned short)v0[q]) << 16), c0, acc[q]);
  }
  float si = g.rsi[wid];
  u16x8 o;
#pragma unroll
  for (int q = 0; q < 8; ++q) o[q] = f2bf(acc[q] * si);
  *(u16x8*)&g.out[(size_t)wid * g.stride + g.ooff + sub * 8] = o;
}

// ---------------- MFMA GEMM ----------------
// H[M x NW*64] = epi(A[M x KCH*128](bf16) @ (Whi+Wlo)[KCH*128 x NW*64])
// W stored transposed [n][k] bf16, hi/lo planes. Block = 4 waves, 64 rows.

template <int KCH, int NW>
__global__ __launch_bounds__(256) void k_mgemm(
    const unsigned short* __restrict__ A,
    const unsigned short* __restrict__ Whi, const unsigned short* __restrict__ Wlo,
    const float* __restrict__ b0, const float* __restrict__ b1,
    float scale, int lrelu_on,
    float* __restrict__ H, int ldh, unsigned short* __restrict__ Hb, int M) {
  constexpr int KP = KCH * 128;
  int t = threadIdx.x;
  int w = t >> 6, l = t & 63;
  int lo16 = l & 15, hi4 = l >> 4;
  int m0 = blockIdx.x * 64;
  f32x4 acc[4][NW] = {};
  for (int s = 0; s < KP / 32; ++s) {
    int kbase = s * 32 + hi4 * 8;
    bf16x8 af[4];
#pragma unroll
    for (int mf = 0; mf < 4; ++mf) {
      int row = m0 + mf * 16 + lo16;
      row = row < M ? row : M - 1;  // clamp; OOB rows never stored
      af[mf] = *(const bf16x8*)&A[(size_t)row * KP + kbase];
    }
#pragma unroll
    for (int nf = 0; nf < NW; ++nf) {
      int n = (w * NW + nf) * 16 + lo16;
      bf16x8 bh = *(const bf16x8*)&Whi[(size_t)n * KP + kbase];
      bf16x8 bl = *(const bf16x8*)&Wlo[(size_t)n * KP + kbase];
#pragma unroll
      for (int mf = 0; mf < 4; ++mf) {
        acc[mf][nf] = __builtin_amdgcn_mfma_f32_16x16x32_bf16(af[mf], bh, acc[mf][nf], 0, 0, 0);
        acc[mf][nf] = __builtin_amdgcn_mfma_f32_16x16x32_bf16(af[mf], bl, acc[mf][nf], 0, 0, 0);
      }
    }
  }
#pragma unroll
  for (int nf = 0; nf < NW; ++nf) {
    int col = (w * NW + nf) * 16 + lo16;
    float bs = b0[col];
    if (b1) bs += b1[col];
#pragma unroll
    for (int mf = 0; mf < 4; ++mf) {
#pragma unroll
      for (int r = 0; r < 4; ++r) {
        int row = m0 + mf * 16 + hi4 * 4 + r;
        if (row < M) {
          float o = scale * (acc[mf][nf][r] + bs);
          if (lrelu_on) o = o >= 0.f ? o : LRELU * o;
          H[(size_t)row * ldh + col] = o;
          if (Hb) Hb[(size_t)row * ldh + col] = f2bf(o);
        }
      }
    }
  }
}

// ---------------- host ----------------

extern "C" void kernel_launch(void* const* d_in, const int* in_sizes, int n_in,
                              void* d_out, int out_size, void* d_ws, size_t ws_size,
                              hipStream_t stream) {
  const float* xu = (const float*)d_in[0];
  const float* xn = (const float*)d_in[1];
  const float* xs = (const float*)d_in[2];
  const float* W1 = (const float*)d_in[3];
  const float* b1 = (const float*)d_in[4];
  const float* W2 = (const float*)d_in[5];
  const float* b2 = (const float*)d_in[6];
  const float* Wu = (const float*)d_in[7];
  const float* bu = (const float*)d_in[8];
  const float* Wn = (const float*)d_in[9];
  const float* bn = (const float*)d_in[10];
  const float* Wsrc = (const float*)d_in[11];
  const float* bsrc = (const float*)d_in[12];
  const int* SRC[5] = {(const int*)d_in[13], (const int*)d_in[15], (const int*)d_in[17],
                       (const int*)d_in[19], (const int*)d_in[21]};
  const int* DST[5] = {(const int*)d_in[14], (const int*)d_in[16], (const int*)d_in[18],
                       (const int*)d_in[20], (const int*)d_in[22]};

  // ---- workspace layout (~69.6 MB) ----
  int* ws_i = (int*)d_ws;
  int* cnt = ws_i;                          // 284000 (dout + din regions)
  int* rp = ws_i + 284000;                  // 142008
  int* csr = ws_i + 426008;                 // 1400000
  int* pos = ws_i + 1826008;                // 1400000
  int* csums = ws_i + 3226008;              // 320
  float* rs = (float*)(ws_i + 3226328);     // 284000
  unsigned short* wt = (unsigned short*)(rs + 284000);    // 376832
  unsigned short* aggU = wt + 376832;       // 50000*256
  unsigned short* aggN = aggU + 12800000;   // 20000*256
  unsigned short* aggS = aggN + 5120000;    // 2000*128
  unsigned short* xbU = aggS + 256000;      // 50000*128
  unsigned short* xbN = xbU + 6400000;      // 20000*128
  unsigned short* xbS = xbN + 2560000;      // 2000*128

  // wt sub-offsets (hi, lo consecutive per job)
  unsigned short* L1U_h = wt, * L1U_l = wt + 32768;
  unsigned short* L1N_h = wt + 65536, * L1N_l = wt + 98304;
  unsigned short* L1S_h = wt + 131072, * L1S_l = wt + 147456;
  unsigned short* L2U_h = wt + 163840, * L2U_l = wt + 196608;
  unsigned short* L2N_h = wt + 229376, * L2N_l = wt + 262144;
  unsigned short* L2S_h = wt + 294912, * L2S_l = wt + 311296;
  unsigned short* PU_h = wt + 327680, * PU_l = wt + 335872;
  unsigned short* PN_h = wt + 344064, * PN_l = wt + 352256;
  unsigned short* PS_h = wt + 360448, * PS_l = wt + 368640;

  // ---- d_out layout ----
  float* outf = (float*)d_out;
  float* ou = outf;                 // 50000*64
  float* on = outf + 3200000;       // 20000*64
  float* osrc = outf + 4480000;     // 2000*64
  float* hu = outf + 4608000;       // 50000*128
  float* hn = outf + 11008000;      // 20000*128
  float* hs = outf + 13568000;      // 2000*128

  // ---- graph build ----
  hipMemsetAsync(cnt, 0, (size_t)284000 * 4, stream);
  B1Args ba;
  for (int r = 0; r < 5; ++r)
    ba.rel[r] = {SRC[r], DST[r], cnt + DOUT_OFF[r], cnt + DIN_OFF[r],
                 pos + CSR_OFF[r], REL_E[r]};
  k_build1<<<5470, 256, 0, stream>>>(ba);
  k_rs<<<1110, 256, 0, stream>>>(cnt, rs, 284000);
  ScanArgs sa;
  for (int r = 0; r < 5; ++r) {
    sa.cnt[r] = cnt + DIN_OFF[r];
    sa.rp[r] = rp + RP_OFF[r];
    sa.n[r] = REL_ND[r];
  }
  sa.csums = csums;
  k_scan1<<<140, 256, 0, stream>>>(sa);
  k_scan2<<<1, 64, 0, stream>>>(sa);
  k_scan3<<<140, 256, 0, stream>>>(sa);
  B2Args b2a;
  for (int r = 0; r < 5; ++r)
    b2a.rel[r] = {SRC[r], DST[r], rp + RP_OFF[r], pos + CSR_OFF[r],
                  csr + CSR_OFF[r], REL_E[r]};
  k_build2<<<5470, 256, 0, stream>>>(b2a);

  // ---- weight prep (transpose + hi/lo split) ----
  PrepArgs pa;
  pa.j[0] = {W1, W1 + 2 * 16384, L1U_h, L1U_l, 128, 8, 0};
  pa.j[1] = {W1 + 16384, W1 + 3 * 16384, L1N_h, L1N_l, 128, 8, 128};
  pa.j[2] = {W1 + 4 * 16384, nullptr, L1S_h, L1S_l, 128, 7, 256};
  pa.j[3] = {W2, W2 + 2 * 16384, L2U_h, L2U_l, 128, 8, 320};
  pa.j[4] = {W2 + 16384, W2 + 3 * 16384, L2N_h, L2N_l, 128, 8, 448};
  pa.j[5] = {W2 + 4 * 16384, nullptr, L2S_h, L2S_l, 128, 7, 576};
  pa.j[6] = {Wu, nullptr, PU_h, PU_l, 64, 7, 640};
  pa.j[7] = {Wn, nullptr, PN_h, PN_l, 64, 7, 672};
  pa.j[8] = {Wsrc, nullptr, PS_h, PS_l, 64, 7, 704};
  k_wprep<<<736, 256, 0, stream>>>(pa);

  // ---- bf16 feature tables for layer-1 gather (one launch) ----
  CvtArgs ca;
  ca.j[0] = {xu, xbU, kNU * 32, 0};
  ca.j[1] = {xn, xbN, kNN * 32, 6250};
  ca.j[2] = {xs, xbS, kNS * 32, 8750};
  k_f2bf3<<<9000, 256, 0, stream>>>(ca);

  // ---- hetero layer: gather per relation, then MFMA GEMMs ----
  auto layer = [&](const unsigned short* Uh, const unsigned short* Ul,
                   const unsigned short* Nh, const unsigned short* Nl,
                   const unsigned short* Sh, const unsigned short* Sl,
                   const float* bl) {
    const unsigned short* XIN[5] = {xbU, xbU, xbN, xbS, xbN};
    unsigned short* OUT[5] = {aggU, aggN, aggU, aggN, aggS};
    const int OSTR[5] = {256, 256, 256, 256, 128};
    const int OOFF[5] = {0, 0, 128, 128, 0};
    GArgs ga;
    for (int r = 0; r < 5; ++r)
      ga.rel[r] = {rp + RP_OFF[r], csr + CSR_OFF[r], XIN[r], rs + DOUT_OFF[r],
                   rs + DIN_OFF[r], OUT[r], OSTR[r], OOFF[r], REL_ND[r]};
    k_gather<<<8875, 256, 0, stream>>>(ga);
    k_mgemm<2, 2><<<782, 256, 0, stream>>>(aggU, Uh, Ul, bl, bl + 2 * 128,
        0.5f, 1, hu, 128, xbU, kNU);
    k_mgemm<2, 2><<<313, 256, 0, stream>>>(aggN, Nh, Nl, bl + 128, bl + 3 * 128,
        0.5f, 1, hn, 128, xbN, kNN);
    k_mgemm<1, 2><<<32, 256, 0, stream>>>(aggS, Sh, Sl, bl + 4 * 128, nullptr,
        1.0f, 1, hs, 128, xbS, kNS);
  };

  // layer 1: x -> h1 (f32 into d_out h-slots, bf16 into xb* for next stage)
  layer(L1U_h, L1U_l, L1N_h, L1N_l, L1S_h, L1S_l, b1);
  // layer 2: h1 -> h2 (gather reads xb*=h1 before mgemm overwrites with h2)
  layer(L2U_h, L2U_l, L2N_h, L2N_l, L2S_h, L2S_l, b2);

  // ---- output projections (read bf16 h2 from xb*) ----
  k_mgemm<1, 1><<<782, 256, 0, stream>>>(xbU, PU_h, PU_l, bu, nullptr,
      1.0f, 0, ou, 64, nullptr, kNU);
  k_mgemm<1, 1><<<313, 256, 0, stream>>>(xbN, PN_h, PN_l, bn, nullptr,
      1.0f, 0, on, 64, nullptr, kNN);
  k_mgemm<1, 1><<<32, 256, 0, stream>>>(xbS, PS_h, PS_l, bsrc, nullptr,
      1.0f, 0, osrc, 64, nullptr, kNS);
}

// Round 6
// 461.368 us; speedup vs baseline: 2.5697x; 1.1013x over previous
//
#include <hip/hip_runtime.h>

#define LRELU 0.01f

// ---------------- problem constants ----------------
// relations: 0 follows U->U, 1 posts U->N, 2 posted_by N->U, 3 publishes S->N, 4 published_by N->S
static const int kNU = 50000, kNN = 20000, kNS = 2000;
static const int REL_E[5]  = {500000, 300000, 300000, 150000, 150000};
static const int REL_ND[5] = {50000, 20000, 50000, 20000, 2000};
static const int DOUT_OFF[5] = {0, 100000, 170000, 240000, 262000};
static const int DIN_OFF[5]  = {50000, 150000, 190000, 242000, 282000};
static const int RP_OFF[5]   = {0, 50001, 70002, 120003, 140004};
static const int CSR_OFF[5]  = {0, 500000, 800000, 1100000, 1250000};

using bf16x8 = __attribute__((ext_vector_type(8))) short;
using u16x8  = __attribute__((ext_vector_type(8))) unsigned short;
using f32x4  = __attribute__((ext_vector_type(4))) float;

__device__ __forceinline__ float bf2f(unsigned short u) {
  return __uint_as_float(((unsigned)u) << 16);
}
__device__ __forceinline__ unsigned short f2bf(float f) {  // RNE
  unsigned u = __float_as_uint(f);
  u += 0x7FFFu + ((u >> 16) & 1u);
  return (unsigned short)(u >> 16);
}

// ---------------- fused setup: build1 (atomic-bound) + wprep + f2bf (hidden) ----------------

struct RelB1 { const int* src; const int* dst; int* dout; int* din; int* pos; int E; };
struct PrepJob { const float* W0; const float* W128; unsigned short* hi;
                 unsigned short* lo; int NOUT; int lgK; int bstart; };
struct CvtJob { const float* in; unsigned short* out; int n4; int bstart; };
struct SetupArgs { RelB1 rel[5]; PrepJob pj[9]; CvtJob cj[3]; };

__global__ __launch_bounds__(256) void k_setup(SetupArgs a) {
  int bx = blockIdx.x;
  int t = threadIdx.x;
  if (bx < 5470) {
    // graph count: dout atomic + din atomic (returned value = CSR slot)
    constexpr int ESTART[6] = {0, 1954, 3126, 4298, 4884, 5470};
    int r = 0;
    while (bx >= ESTART[r + 1]) ++r;
    RelB1 e = a.rel[r];
    int i = (bx - ESTART[r]) * 256 + t;
    if (i < e.E) {
      atomicAdd(&e.dout[e.src[i]], 1);
      int p = atomicAdd(&e.din[e.dst[i]], 1);
      e.pos[i] = p;
    }
  } else if (bx < 6206) {
    // weight prep: transpose + hi/lo bf16 split
    int b = bx - 5470, ji = 0;
    while (ji < 8 && b >= a.pj[ji + 1].bstart) ++ji;
    PrepJob p = a.pj[ji];
    int idx = (b - p.bstart) * 256 + t;
    int K = 1 << p.lgK;
    int n = idx >> p.lgK, k = idx & (K - 1);
    if (n >= p.NOUT) return;
    float w = (k < 128) ? p.W0[k * p.NOUT + n] : p.W128[(k - 128) * p.NOUT + n];
    unsigned short h = f2bf(w);
    float res = w - bf2f(h);
    p.hi[n * K + k] = h;
    p.lo[n * K + k] = f2bf(res);
  } else {
    // f32 -> bf16 feature tables
    int b = bx - 6206, ji = 0;
    while (ji < 2 && b >= a.cj[ji + 1].bstart) ++ji;
    CvtJob p = a.cj[ji];
    int i = (b - p.bstart) * 256 + t;
    if (i >= p.n4) return;
    float4 v = ((const float4*)p.in)[i];
    ushort4 o = {f2bf(v.x), f2bf(v.y), f2bf(v.z), f2bf(v.w)};
    ((ushort4*)p.out)[i] = o;
  }
}

// ---------------- fused rs + scan1 ----------------

struct ScanArgs { const int* cnt[5]; int* rp[5]; int n[5]; int* csums; };
struct RsScanArgs { const int* cnt; float* rs; ScanArgs sa; };

__global__ __launch_bounds__(256) void k_rs_scan1(RsScanArgs a) {
  int bx = blockIdx.x;
  int t = threadIdx.x;
  if (bx < 1110) {
    int i = bx * 256 + t;
    if (i < 284000) {
      int c = a.cnt[i];
      a.rs[i] = rsqrtf((float)(c > 1 ? c : 1));
    }
    return;
  }
  bx -= 1110;
  constexpr int CSTART[6] = {0, 49, 69, 118, 138, 140};
  int r = 0;
  while (bx >= CSTART[r + 1]) ++r;
  int chunk = bx - CSTART[r];
  int n = a.sa.n[r];
  int base = chunk * 1024;
  const int* cnt = a.sa.cnt[r];
  int s = 0;
#pragma unroll
  for (int j = 0; j < 4; ++j) {
    int idx = base + j * 256 + t;
    if (idx < n) s += cnt[idx];
  }
  __shared__ int sd[256];
  sd[t] = s;
  __syncthreads();
  for (int off = 128; off > 0; off >>= 1) {
    if (t < off) sd[t] += sd[t + off];
    __syncthreads();
  }
  if (t == 0) a.sa.csums[r * 64 + chunk] = sd[0];
}

__global__ __launch_bounds__(64) void k_scan2(ScanArgs a) {
  constexpr int NCH[5] = {49, 20, 49, 20, 2};
  int r = threadIdx.x;
  if (r < 5) {
    int run = 0;
    for (int i = 0; i < NCH[r]; ++i) {
      int v = a.csums[r * 64 + i];
      a.csums[r * 64 + i] = run;
      run += v;
    }
    a.rp[r][a.n[r]] = run;
  }
}

__global__ __launch_bounds__(256) void k_scan3(ScanArgs a) {
  constexpr int CSTART[6] = {0, 49, 69, 118, 138, 140};
  int bx = blockIdx.x, r = 0;
  while (bx >= CSTART[r + 1]) ++r;
  int chunk = bx - CSTART[r];
  int n = a.n[r];
  int base = chunk * 1024;
  const int* cnt = a.cnt[r];
  int* rp = a.rp[r];
  int t = threadIdx.x;
  int idx0 = base + t * 4;
  int v[4];
#pragma unroll
  for (int j = 0; j < 4; ++j) v[j] = (idx0 + j < n) ? cnt[idx0 + j] : 0;
  int tsum = v[0] + v[1] + v[2] + v[3];
  __shared__ int sd[256];
  sd[t] = tsum;
  __syncthreads();
  for (int s = 1; s < 256; s <<= 1) {
    int add = (t >= s) ? sd[t - s] : 0;
    __syncthreads();
    sd[t] += add;
    __syncthreads();
  }
  int off = a.csums[r * 64 + chunk] + sd[t] - tsum;
#pragma unroll
  for (int j = 0; j < 4; ++j) {
    if (idx0 + j < n) rp[idx0 + j] = off;
    off += v[j];
  }
}

// ---------------- build2: atomic-free CSR scatter ----------------

struct RelB2 { const int* src; const int* dst; const int* rp; const int* pos; int* csr; int E; };
struct B2Args { RelB2 rel[5]; };

__global__ __launch_bounds__(256) void k_build2(B2Args a) {
  constexpr int ESTART[6] = {0, 1954, 3126, 4298, 4884, 5470};
  int bx = blockIdx.x, r = 0;
  while (bx >= ESTART[r + 1]) ++r;
  RelB2 f = a.rel[r];
  int i = (bx - ESTART[r]) * 256 + threadIdx.x;
  if (i < f.E) {
    int d = f.dst[i];
    f.csr[f.rp[d] + f.pos[i]] = f.src[i];
  }
}

// ---------------- gather: 16 lanes/row, 16-edge batches, shfl-broadcast ----------------
// Per 16-edge batch: one coalesced csr read + 16 parallel rso gathers, then
// row loads broadcast via width-16 shfl, 8 in flight.

struct RelG {
  const int* rp; const int* csr; const unsigned short* xb;
  const float* rso; const float* rsi;
  unsigned short* out; int stride; int ooff; int nd;
};
struct GArgs { RelG rel[5]; };

#define GROW(vv, cc)                                                              \
  _Pragma("unroll") for (int q = 0; q < 8; ++q)                                   \
      acc[q] = fmaf(__uint_as_float(((unsigned)(unsigned short)vv[q]) << 16), cc, acc[q]);

__global__ __launch_bounds__(256) void k_gather(GArgs a) {
  constexpr int GSTART[6] = {0, 3125, 4375, 7500, 8750, 8875};
  int bx = blockIdx.x, r = 0;
  while (bx >= GSTART[r + 1]) ++r;
  RelG g = a.rel[r];
  int t = threadIdx.x;
  int sub = t & 15;
  int wid = (bx - GSTART[r]) * 16 + (t >> 4);
  if (wid >= g.nd) return;
  int e0 = g.rp[wid], e1 = g.rp[wid + 1];
  const unsigned short* xb = g.xb;
  float acc[8] = {};
  for (int base = e0; base < e1; base += 16) {
    int m = e1 - base;
    if (m > 16) m = 16;
    int ei = base + (sub < m ? sub : 0);
    int se = g.csr[ei];       // 16 edges loaded in parallel (coalesced)
    float sc = g.rso[se];     // 16 scale gathers in parallel
    int j = 0;
    for (; j + 8 <= m; j += 8) {
      int s0 = __shfl(se, j, 16), s1 = __shfl(se, j + 1, 16);
      int s2 = __shfl(se, j + 2, 16), s3 = __shfl(se, j + 3, 16);
      int s4 = __shfl(se, j + 4, 16), s5 = __shfl(se, j + 5, 16);
      int s6 = __shfl(se, j + 6, 16), s7 = __shfl(se, j + 7, 16);
      float c0 = __shfl(sc, j, 16), c1 = __shfl(sc, j + 1, 16);
      float c2 = __shfl(sc, j + 2, 16), c3 = __shfl(sc, j + 3, 16);
      float c4 = __shfl(sc, j + 4, 16), c5 = __shfl(sc, j + 5, 16);
      float c6 = __shfl(sc, j + 6, 16), c7 = __shfl(sc, j + 7, 16);
      bf16x8 v0 = *(const bf16x8*)&xb[(size_t)s0 * 128 + sub * 8];
      bf16x8 v1 = *(const bf16x8*)&xb[(size_t)s1 * 128 + sub * 8];
      bf16x8 v2 = *(const bf16x8*)&xb[(size_t)s2 * 128 + sub * 8];
      bf16x8 v3 = *(const bf16x8*)&xb[(size_t)s3 * 128 + sub * 8];
      bf16x8 v4 = *(const bf16x8*)&xb[(size_t)s4 * 128 + sub * 8];
      bf16x8 v5 = *(const bf16x8*)&xb[(size_t)s5 * 128 + sub * 8];
      bf16x8 v6 = *(const bf16x8*)&xb[(size_t)s6 * 128 + sub * 8];
      bf16x8 v7 = *(const bf16x8*)&xb[(size_t)s7 * 128 + sub * 8];
      GROW(v0, c0) GROW(v1, c1) GROW(v2, c2) GROW(v3, c3)
      GROW(v4, c4) GROW(v5, c5) GROW(v6, c6) GROW(v7, c7)
    }
    for (; j < m; ++j) {
      int s0 = __shfl(se, j, 16);
      float c0 = __shfl(sc, j, 16);
      bf16x8 v0 = *(const bf16x8*)&xb[(size_t)s0 * 128 + sub * 8];
      GROW(v0, c0)
    }
  }
  float si = g.rsi[wid];
  u16x8 o;
#pragma unroll
  for (int q = 0; q < 8; ++q) o[q] = f2bf(acc[q] * si);
  *(u16x8*)&g.out[(size_t)wid * g.stride + g.ooff + sub * 8] = o;
}

// ---------------- MFMA GEMM (fused 3 dst-types per launch) ----------------

struct MJob { const unsigned short* A; const unsigned short* Wh; const unsigned short* Wl;
              const float* b0; const float* b1; float scale; int lrelu;
              float* H; int ldh; unsigned short* Hb; int M; int bstart; };
struct MArgs { MJob j[3]; };

template <int KCH, int NW>
__device__ __forceinline__ void mgemm_body(const MJob& p, int bxl) {
  constexpr int KP = KCH * 128;
  int t = threadIdx.x;
  int w = t >> 6, l = t & 63;
  int lo16 = l & 15, hi4 = l >> 4;
  int m0 = bxl * 64;
  int M = p.M;
  const unsigned short* A = p.A;
  f32x4 acc[4][NW] = {};
  for (int s = 0; s < KP / 32; ++s) {
    int kbase = s * 32 + hi4 * 8;
    bf16x8 af[4];
#pragma unroll
    for (int mf = 0; mf < 4; ++mf) {
      int row = m0 + mf * 16 + lo16;
      row = row < M ? row : M - 1;  // clamp; OOB rows never stored
      af[mf] = *(const bf16x8*)&A[(size_t)row * KP + kbase];
    }
#pragma unroll
    for (int nf = 0; nf < NW; ++nf) {
      int n = (w * NW + nf) * 16 + lo16;
      bf16x8 bh = *(const bf16x8*)&p.Wh[(size_t)n * KP + kbase];
      bf16x8 bl = *(const bf16x8*)&p.Wl[(size_t)n * KP + kbase];
#pragma unroll
      for (int mf = 0; mf < 4; ++mf) {
        acc[mf][nf] = __builtin_amdgcn_mfma_f32_16x16x32_bf16(af[mf], bh, acc[mf][nf], 0, 0, 0);
        acc[mf][nf] = __builtin_amdgcn_mfma_f32_16x16x32_bf16(af[mf], bl, acc[mf][nf], 0, 0, 0);
      }
    }
  }
#pragma unroll
  for (int nf = 0; nf < NW; ++nf) {
    int col = (w * NW + nf) * 16 + lo16;
    float bs = p.b0[col];
    if (p.b1) bs += p.b1[col];
#pragma unroll
    for (int mf = 0; mf < 4; ++mf) {
#pragma unroll
      for (int rr = 0; rr < 4; ++rr) {
        int row = m0 + mf * 16 + hi4 * 4 + rr;
        if (row < M) {
          float o = p.scale * (acc[mf][nf][rr] + bs);
          if (p.lrelu) o = o >= 0.f ? o : LRELU * o;
          if (p.H) p.H[(size_t)row * p.ldh + col] = o;
          if (p.Hb) p.Hb[(size_t)row * p.ldh + col] = f2bf(o);
        }
      }
    }
  }
}

__global__ __launch_bounds__(256) void k_mgemm3(MArgs a) {
  int bx = blockIdx.x;
  if (bx < a.j[1].bstart)      mgemm_body<2, 2>(a.j[0], bx);
  else if (bx < a.j[2].bstart) mgemm_body<2, 2>(a.j[1], bx - a.j[1].bstart);
  else                         mgemm_body<1, 2>(a.j[2], bx - a.j[2].bstart);
}

__global__ __launch_bounds__(256) void k_proj3(MArgs a) {
  int bx = blockIdx.x;
  if (bx < a.j[1].bstart)      mgemm_body<1, 1>(a.j[0], bx);
  else if (bx < a.j[2].bstart) mgemm_body<1, 1>(a.j[1], bx - a.j[1].bstart);
  else                         mgemm_body<1, 1>(a.j[2], bx - a.j[2].bstart);
}

// ---------------- host ----------------

extern "C" void kernel_launch(void* const* d_in, const int* in_sizes, int n_in,
                              void* d_out, int out_size, void* d_ws, size_t ws_size,
                              hipStream_t stream) {
  const float* xu = (const float*)d_in[0];
  const float* xn = (const float*)d_in[1];
  const float* xs = (const float*)d_in[2];
  const float* W1 = (const float*)d_in[3];
  const float* b1 = (const float*)d_in[4];
  const float* W2 = (const float*)d_in[5];
  const float* b2 = (const float*)d_in[6];
  const float* Wu = (const float*)d_in[7];
  const float* bu = (const float*)d_in[8];
  const float* Wn = (const float*)d_in[9];
  const float* bn = (const float*)d_in[10];
  const float* Wsrc = (const float*)d_in[11];
  const float* bsrc = (const float*)d_in[12];
  const int* SRC[5] = {(const int*)d_in[13], (const int*)d_in[15], (const int*)d_in[17],
                       (const int*)d_in[19], (const int*)d_in[21]};
  const int* DST[5] = {(const int*)d_in[14], (const int*)d_in[16], (const int*)d_in[18],
                       (const int*)d_in[20], (const int*)d_in[22]};

  // ---- workspace layout (~69.6 MB) ----
  int* ws_i = (int*)d_ws;
  int* cnt = ws_i;                          // 284000 (dout + din regions)
  int* rp = ws_i + 284000;                  // 142008
  int* csr = ws_i + 426008;                 // 1400000
  int* pos = ws_i + 1826008;                // 1400000
  int* csums = ws_i + 3226008;              // 320
  float* rs = (float*)(ws_i + 3226328);     // 284000
  unsigned short* wt = (unsigned short*)(rs + 284000);    // 376832
  unsigned short* aggU = wt + 376832;       // 50000*256
  unsigned short* aggN = aggU + 12800000;   // 20000*256
  unsigned short* aggS = aggN + 5120000;    // 2000*128
  unsigned short* xbU = aggS + 256000;      // 50000*128
  unsigned short* xbN = xbU + 6400000;      // 20000*128
  unsigned short* xbS = xbN + 2560000;      // 2000*128

  // wt sub-offsets (hi, lo consecutive per job)
  unsigned short* L1U_h = wt, * L1U_l = wt + 32768;
  unsigned short* L1N_h = wt + 65536, * L1N_l = wt + 98304;
  unsigned short* L1S_h = wt + 131072, * L1S_l = wt + 147456;
  unsigned short* L2U_h = wt + 163840, * L2U_l = wt + 196608;
  unsigned short* L2N_h = wt + 229376, * L2N_l = wt + 262144;
  unsigned short* L2S_h = wt + 294912, * L2S_l = wt + 311296;
  unsigned short* PU_h = wt + 327680, * PU_l = wt + 335872;
  unsigned short* PN_h = wt + 344064, * PN_l = wt + 352256;
  unsigned short* PS_h = wt + 360448, * PS_l = wt + 368640;

  // ---- d_out layout ----
  float* outf = (float*)d_out;
  float* ou = outf;                 // 50000*64
  float* on = outf + 3200000;       // 20000*64
  float* osrc = outf + 4480000;     // 2000*64
  float* hu = outf + 4608000;       // 50000*128
  float* hn = outf + 11008000;      // 20000*128
  float* hs = outf + 13568000;      // 2000*128

  // ---- fused setup: graph count + weight prep + feature convert ----
  hipMemsetAsync(cnt, 0, (size_t)284000 * 4, stream);
  SetupArgs su;
  for (int r = 0; r < 5; ++r)
    su.rel[r] = {SRC[r], DST[r], cnt + DOUT_OFF[r], cnt + DIN_OFF[r],
                 pos + CSR_OFF[r], REL_E[r]};
  su.pj[0] = {W1, W1 + 2 * 16384, L1U_h, L1U_l, 128, 8, 0};
  su.pj[1] = {W1 + 16384, W1 + 3 * 16384, L1N_h, L1N_l, 128, 8, 128};
  su.pj[2] = {W1 + 4 * 16384, nullptr, L1S_h, L1S_l, 128, 7, 256};
  su.pj[3] = {W2, W2 + 2 * 16384, L2U_h, L2U_l, 128, 8, 320};
  su.pj[4] = {W2 + 16384, W2 + 3 * 16384, L2N_h, L2N_l, 128, 8, 448};
  su.pj[5] = {W2 + 4 * 16384, nullptr, L2S_h, L2S_l, 128, 7, 576};
  su.pj[6] = {Wu, nullptr, PU_h, PU_l, 64, 7, 640};
  su.pj[7] = {Wn, nullptr, PN_h, PN_l, 64, 7, 672};
  su.pj[8] = {Wsrc, nullptr, PS_h, PS_l, 64, 7, 704};
  su.cj[0] = {xu, xbU, kNU * 32, 0};
  su.cj[1] = {xn, xbN, kNN * 32, 6250};
  su.cj[2] = {xs, xbS, kNS * 32, 8750};
  k_setup<<<15206, 256, 0, stream>>>(su);

  // ---- rs + scan ----
  ScanArgs sa;
  for (int r = 0; r < 5; ++r) {
    sa.cnt[r] = cnt + DIN_OFF[r];
    sa.rp[r] = rp + RP_OFF[r];
    sa.n[r] = REL_ND[r];
  }
  sa.csums = csums;
  RsScanArgs rsa;
  rsa.cnt = cnt;
  rsa.rs = rs;
  rsa.sa = sa;
  k_rs_scan1<<<1250, 256, 0, stream>>>(rsa);
  k_scan2<<<1, 64, 0, stream>>>(sa);
  k_scan3<<<140, 256, 0, stream>>>(sa);

  B2Args b2a;
  for (int r = 0; r < 5; ++r)
    b2a.rel[r] = {SRC[r], DST[r], rp + RP_OFF[r], pos + CSR_OFF[r],
                  csr + CSR_OFF[r], REL_E[r]};
  k_build2<<<5470, 256, 0, stream>>>(b2a);

  // ---- hetero layers: gather + fused MFMA GEMM ----
  auto layer = [&](const unsigned short* Uh, const unsigned short* Ul,
                   const unsigned short* Nh, const unsigned short* Nl,
                   const unsigned short* Sh, const unsigned short* Sl,
                   const float* bl, bool last) {
    const unsigned short* XIN[5] = {xbU, xbU, xbN, xbS, xbN};
    unsigned short* OUT[5] = {aggU, aggN, aggU, aggN, aggS};
    const int OSTR[5] = {256, 256, 256, 256, 128};
    const int OOFF[5] = {0, 0, 128, 128, 0};
    GArgs ga;
    for (int r = 0; r < 5; ++r)
      ga.rel[r] = {rp + RP_OFF[r], csr + CSR_OFF[r], XIN[r], rs + DOUT_OFF[r],
                   rs + DIN_OFF[r], OUT[r], OSTR[r], OOFF[r], REL_ND[r]};
    k_gather<<<8875, 256, 0, stream>>>(ga);
    MArgs ma;
    // layer-1 f32 H is dead (layer-2 consumes the bf16 copy) -> H=nullptr
    ma.j[0] = {aggU, Uh, Ul, bl, bl + 2 * 128, 0.5f, 1,
               last ? hu : nullptr, 128, xbU, kNU, 0};
    ma.j[1] = {aggN, Nh, Nl, bl + 128, bl + 3 * 128, 0.5f, 1,
               last ? hn : nullptr, 128, xbN, kNN, 782};
    ma.j[2] = {aggS, Sh, Sl, bl + 4 * 128, nullptr, 1.0f, 1,
               last ? hs : nullptr, 128, xbS, kNS, 1095};
    k_mgemm3<<<1127, 256, 0, stream>>>(ma);
  };

  layer(L1U_h, L1U_l, L1N_h, L1N_l, L1S_h, L1S_l, b1, false);  // x -> h1 (bf16 only)
  layer(L2U_h, L2U_l, L2N_h, L2N_l, L2S_h, L2S_l, b2, true);   // h1 -> h2 (f32 + bf16)

  // ---- output projections (read bf16 h2 from xb*) ----
  MArgs pm;
  pm.j[0] = {xbU, PU_h, PU_l, bu, nullptr, 1.0f, 0, ou, 64, nullptr, kNU, 0};
  pm.j[1] = {xbN, PN_h, PN_l, bn, nullptr, 1.0f, 0, on, 64, nullptr, kNN, 782};
  pm.j[2] = {xbS, PS_h, PS_l, bsrc, nullptr, 1.0f, 0, osrc, 64, nullptr, kNS, 1095};
  k_proj3<<<1127, 256, 0, stream>>>(pm);
}

// Round 7
// 449.229 us; speedup vs baseline: 2.6391x; 1.0270x over previous
//
#include <hip/hip_runtime.h>

#define LRELU 0.01f

// ---------------- problem constants ----------------
// relations: 0 follows U->U, 1 posts U->N, 2 posted_by N->U, 3 publishes S->N, 4 published_by N->S
static const int kNU = 50000, kNN = 20000, kNS = 2000;
static const int REL_E[5]  = {500000, 300000, 300000, 150000, 150000};
static const int REL_ND[5] = {50000, 20000, 50000, 20000, 2000};
// counter-index offsets (scaled by PAD=8 when forming pointers)
static const int DOUT_OFF[5] = {0, 100000, 170000, 240000, 262000};
static const int DIN_OFF[5]  = {50000, 150000, 190000, 242000, 282000};
static const int RP_OFF[5]   = {0, 50001, 70002, 120003, 140004};
static const int CSR_OFF[5]  = {0, 500000, 800000, 1100000, 1250000};

using bf16x8 = __attribute__((ext_vector_type(8))) short;
using u16x8  = __attribute__((ext_vector_type(8))) unsigned short;
using f32x4  = __attribute__((ext_vector_type(4))) float;

__device__ __forceinline__ float bf2f(unsigned short u) {
  return __uint_as_float(((unsigned)u) << 16);
}
__device__ __forceinline__ unsigned short f2bf(float f) {  // RNE
  unsigned u = __float_as_uint(f);
  u += 0x7FFFu + ((u >> 16) & 1u);
  return (unsigned short)(u >> 16);
}

// ---------------- fused setup: build1 (atomic-bound) + wprep + f2bf (hidden) ----------------
// Counters are padded to one per 32B sector (stride 8 ints) so memory-side
// RMWs to distinct counters never serialize on the same sector.

struct RelB1 { const int* src; const int* dst; int* dout; int* din; int* pos; int E; };
struct PrepJob { const float* W0; const float* W128; unsigned short* hi;
                 unsigned short* lo; int NOUT; int lgK; int bstart; };
struct CvtJob { const float* in; unsigned short* out; int n4; int bstart; };
struct SetupArgs { RelB1 rel[5]; PrepJob pj[9]; CvtJob cj[3]; };

__global__ __launch_bounds__(256) void k_setup(SetupArgs a) {
  int bx = blockIdx.x;
  int t = threadIdx.x;
  if (bx < 5470) {
    constexpr int ESTART[6] = {0, 1954, 3126, 4298, 4884, 5470};
    int r = 0;
    while (bx >= ESTART[r + 1]) ++r;
    RelB1 e = a.rel[r];
    int i = (bx - ESTART[r]) * 256 + t;
    if (i < e.E) {
      atomicAdd(&e.dout[e.src[i] * 8], 1);
      int p = atomicAdd(&e.din[e.dst[i] * 8], 1);
      e.pos[i] = p;
    }
  } else if (bx < 6206) {
    int b = bx - 5470, ji = 0;
    while (ji < 8 && b >= a.pj[ji + 1].bstart) ++ji;
    PrepJob p = a.pj[ji];
    int idx = (b - p.bstart) * 256 + t;
    int K = 1 << p.lgK;
    int n = idx >> p.lgK, k = idx & (K - 1);
    if (n >= p.NOUT) return;
    float w = (k < 128) ? p.W0[k * p.NOUT + n] : p.W128[(k - 128) * p.NOUT + n];
    unsigned short h = f2bf(w);
    float res = w - bf2f(h);
    p.hi[n * K + k] = h;
    p.lo[n * K + k] = f2bf(res);
  } else {
    int b = bx - 6206, ji = 0;
    while (ji < 2 && b >= a.cj[ji + 1].bstart) ++ji;
    CvtJob p = a.cj[ji];
    int i = (b - p.bstart) * 256 + t;
    if (i >= p.n4) return;
    float4 v = ((const float4*)p.in)[i];
    ushort4 o = {f2bf(v.x), f2bf(v.y), f2bf(v.z), f2bf(v.w)};
    ((ushort4*)p.out)[i] = o;
  }
}

// ---------------- fused rs + scan1 (strided counter reads) ----------------

struct ScanArgs { const int* cnt[5]; int* rp[5]; int n[5]; int* csums; };
struct RsScanArgs { const int* cnt; float* rs; ScanArgs sa; };

__global__ __launch_bounds__(256) void k_rs_scan1(RsScanArgs a) {
  int bx = blockIdx.x;
  int t = threadIdx.x;
  if (bx < 1110) {
    int i = bx * 256 + t;
    if (i < 284000) {
      int c = a.cnt[i * 8];
      a.rs[i] = rsqrtf((float)(c > 1 ? c : 1));
    }
    return;
  }
  bx -= 1110;
  constexpr int CSTART[6] = {0, 49, 69, 118, 138, 140};
  int r = 0;
  while (bx >= CSTART[r + 1]) ++r;
  int chunk = bx - CSTART[r];
  int n = a.sa.n[r];
  int base = chunk * 1024;
  const int* cnt = a.sa.cnt[r];
  int s = 0;
#pragma unroll
  for (int j = 0; j < 4; ++j) {
    int idx = base + j * 256 + t;
    if (idx < n) s += cnt[idx * 8];
  }
  __shared__ int sd[256];
  sd[t] = s;
  __syncthreads();
  for (int off = 128; off > 0; off >>= 1) {
    if (t < off) sd[t] += sd[t + off];
    __syncthreads();
  }
  if (t == 0) a.sa.csums[r * 64 + chunk] = sd[0];
}

// ---------------- scan3: local scan + in-block chunk-prefix (scan2 folded in) ----------------

__global__ __launch_bounds__(256) void k_scan3(ScanArgs a) {
  constexpr int CSTART[6] = {0, 49, 69, 118, 138, 140};
  int bx = blockIdx.x, r = 0;
  while (bx >= CSTART[r + 1]) ++r;
  int chunk = bx - CSTART[r];
  int nch = CSTART[r + 1] - CSTART[r];
  int n = a.n[r];
  int base = chunk * 1024;
  const int* cnt = a.cnt[r];
  int* rp = a.rp[r];
  int t = threadIdx.x;
  int idx0 = base + t * 4;
  int v[4];
#pragma unroll
  for (int j = 0; j < 4; ++j) v[j] = (idx0 + j < n) ? cnt[(idx0 + j) * 8] : 0;
  int tsum = v[0] + v[1] + v[2] + v[3];
  __shared__ int sd[256];
  __shared__ int choff_sh;
  sd[t] = tsum;
  if (t < 64) {  // prefix of earlier chunk sums (raw csums), wave reduce
    int cv = (t < chunk) ? a.csums[r * 64 + t] : 0;
    for (int o = 32; o > 0; o >>= 1) cv += __shfl_down(cv, o);
    if (t == 0) choff_sh = cv;
  }
  __syncthreads();
  for (int s = 1; s < 256; s <<= 1) {
    int add = (t >= s) ? sd[t - s] : 0;
    __syncthreads();
    sd[t] += add;
    __syncthreads();
  }
  int off = choff_sh + sd[t] - tsum;
#pragma unroll
  for (int j = 0; j < 4; ++j) {
    if (idx0 + j < n) rp[idx0 + j] = off;
    off += v[j];
  }
  if (chunk == nch - 1 && t == 255) rp[n] = choff_sh + sd[255];
}

// ---------------- build2: atomic-free CSR scatter ----------------

struct RelB2 { const int* src; const int* dst; const int* rp; const int* pos; int* csr; int E; };
struct B2Args { RelB2 rel[5]; };

__global__ __launch_bounds__(256) void k_build2(B2Args a) {
  constexpr int ESTART[6] = {0, 1954, 3126, 4298, 4884, 5470};
  int bx = blockIdx.x, r = 0;
  while (bx >= ESTART[r + 1]) ++r;
  RelB2 f = a.rel[r];
  int i = (bx - ESTART[r]) * 256 + threadIdx.x;
  if (i < f.E) {
    int d = f.dst[i];
    f.csr[f.rp[d] + f.pos[i]] = f.src[i];
  }
}

// ---------------- gather: 16 lanes/row, 16-edge batches, shfl-broadcast ----------------

struct RelG {
  const int* rp; const int* csr; const unsigned short* xb;
  const float* rso; const float* rsi;
  unsigned short* out; int stride; int ooff; int nd;
};
struct GArgs { RelG rel[5]; };

#define GROW(vv, cc)                                                              \
  _Pragma("unroll") for (int q = 0; q < 8; ++q)                                   \
      acc[q] = fmaf(__uint_as_float(((unsigned)(unsigned short)vv[q]) << 16), cc, acc[q]);

__global__ __launch_bounds__(256) void k_gather(GArgs a) {
  constexpr int GSTART[6] = {0, 3125, 4375, 7500, 8750, 8875};
  int bx = blockIdx.x, r = 0;
  while (bx >= GSTART[r + 1]) ++r;
  RelG g = a.rel[r];
  int t = threadIdx.x;
  int sub = t & 15;
  int wid = (bx - GSTART[r]) * 16 + (t >> 4);
  if (wid >= g.nd) return;
  int e0 = g.rp[wid], e1 = g.rp[wid + 1];
  const unsigned short* xb = g.xb;
  float acc[8] = {};
  for (int base = e0; base < e1; base += 16) {
    int m = e1 - base;
    if (m > 16) m = 16;
    int ei = base + (sub < m ? sub : 0);
    int se = g.csr[ei];       // 16 edges loaded in parallel (coalesced)
    float sc = g.rso[se];     // 16 scale gathers in parallel
    int j = 0;
    for (; j + 8 <= m; j += 8) {
      int s0 = __shfl(se, j, 16), s1 = __shfl(se, j + 1, 16);
      int s2 = __shfl(se, j + 2, 16), s3 = __shfl(se, j + 3, 16);
      int s4 = __shfl(se, j + 4, 16), s5 = __shfl(se, j + 5, 16);
      int s6 = __shfl(se, j + 6, 16), s7 = __shfl(se, j + 7, 16);
      float c0 = __shfl(sc, j, 16), c1 = __shfl(sc, j + 1, 16);
      float c2 = __shfl(sc, j + 2, 16), c3 = __shfl(sc, j + 3, 16);
      float c4 = __shfl(sc, j + 4, 16), c5 = __shfl(sc, j + 5, 16);
      float c6 = __shfl(sc, j + 6, 16), c7 = __shfl(sc, j + 7, 16);
      bf16x8 v0 = *(const bf16x8*)&xb[(size_t)s0 * 128 + sub * 8];
      bf16x8 v1 = *(const bf16x8*)&xb[(size_t)s1 * 128 + sub * 8];
      bf16x8 v2 = *(const bf16x8*)&xb[(size_t)s2 * 128 + sub * 8];
      bf16x8 v3 = *(const bf16x8*)&xb[(size_t)s3 * 128 + sub * 8];
      bf16x8 v4 = *(const bf16x8*)&xb[(size_t)s4 * 128 + sub * 8];
      bf16x8 v5 = *(const bf16x8*)&xb[(size_t)s5 * 128 + sub * 8];
      bf16x8 v6 = *(const bf16x8*)&xb[(size_t)s6 * 128 + sub * 8];
      bf16x8 v7 = *(const bf16x8*)&xb[(size_t)s7 * 128 + sub * 8];
      GROW(v0, c0) GROW(v1, c1) GROW(v2, c2) GROW(v3, c3)
      GROW(v4, c4) GROW(v5, c5) GROW(v6, c6) GROW(v7, c7)
    }
    for (; j < m; ++j) {
      int s0 = __shfl(se, j, 16);
      float c0 = __shfl(sc, j, 16);
      bf16x8 v0 = *(const bf16x8*)&xb[(size_t)s0 * 128 + sub * 8];
      GROW(v0, c0)
    }
  }
  float si = g.rsi[wid];
  u16x8 o;
#pragma unroll
  for (int q = 0; q < 8; ++q) o[q] = f2bf(acc[q] * si);
  *(u16x8*)&g.out[(size_t)wid * g.stride + g.ooff + sub * 8] = o;
}

// ---------------- MFMA GEMM (fused 3 dst-types per launch) ----------------

struct MJob { const unsigned short* A; const unsigned short* Wh; const unsigned short* Wl;
              const float* b0; const float* b1; float scale; int lrelu;
              float* H; int ldh; unsigned short* Hb; int M; int bstart; };
struct MArgs { MJob j[3]; };

template <int KCH, int NW>
__device__ __forceinline__ void mgemm_body(const MJob& p, int bxl) {
  constexpr int KP = KCH * 128;
  int t = threadIdx.x;
  int w = t >> 6, l = t & 63;
  int lo16 = l & 15, hi4 = l >> 4;
  int m0 = bxl * 64;
  int M = p.M;
  const unsigned short* A = p.A;
  f32x4 acc[4][NW] = {};
  for (int s = 0; s < KP / 32; ++s) {
    int kbase = s * 32 + hi4 * 8;
    bf16x8 af[4];
#pragma unroll
    for (int mf = 0; mf < 4; ++mf) {
      int row = m0 + mf * 16 + lo16;
      row = row < M ? row : M - 1;  // clamp; OOB rows never stored
      af[mf] = *(const bf16x8*)&A[(size_t)row * KP + kbase];
    }
#pragma unroll
    for (int nf = 0; nf < NW; ++nf) {
      int n = (w * NW + nf) * 16 + lo16;
      bf16x8 bh = *(const bf16x8*)&p.Wh[(size_t)n * KP + kbase];
      bf16x8 bl = *(const bf16x8*)&p.Wl[(size_t)n * KP + kbase];
#pragma unroll
      for (int mf = 0; mf < 4; ++mf) {
        acc[mf][nf] = __builtin_amdgcn_mfma_f32_16x16x32_bf16(af[mf], bh, acc[mf][nf], 0, 0, 0);
        acc[mf][nf] = __builtin_amdgcn_mfma_f32_16x16x32_bf16(af[mf], bl, acc[mf][nf], 0, 0, 0);
      }
    }
  }
#pragma unroll
  for (int nf = 0; nf < NW; ++nf) {
    int col = (w * NW + nf) * 16 + lo16;
    float bs = p.b0[col];
    if (p.b1) bs += p.b1[col];
#pragma unroll
    for (int mf = 0; mf < 4; ++mf) {
#pragma unroll
      for (int rr = 0; rr < 4; ++rr) {
        int row = m0 + mf * 16 + hi4 * 4 + rr;
        if (row < M) {
          float o = p.scale * (acc[mf][nf][rr] + bs);
          if (p.lrelu) o = o >= 0.f ? o : LRELU * o;
          if (p.H) p.H[(size_t)row * p.ldh + col] = o;
          if (p.Hb) p.Hb[(size_t)row * p.ldh + col] = f2bf(o);
        }
      }
    }
  }
}

__global__ __launch_bounds__(256) void k_mgemm3(MArgs a) {
  int bx = blockIdx.x;
  if (bx < a.j[1].bstart)      mgemm_body<2, 2>(a.j[0], bx);
  else if (bx < a.j[2].bstart) mgemm_body<2, 2>(a.j[1], bx - a.j[1].bstart);
  else                         mgemm_body<1, 2>(a.j[2], bx - a.j[2].bstart);
}

__global__ __launch_bounds__(256) void k_proj3(MArgs a) {
  int bx = blockIdx.x;
  if (bx < a.j[1].bstart)      mgemm_body<1, 1>(a.j[0], bx);
  else if (bx < a.j[2].bstart) mgemm_body<1, 1>(a.j[1], bx - a.j[1].bstart);
  else                         mgemm_body<1, 1>(a.j[2], bx - a.j[2].bstart);
}

// ---------------- host ----------------

extern "C" void kernel_launch(void* const* d_in, const int* in_sizes, int n_in,
                              void* d_out, int out_size, void* d_ws, size_t ws_size,
                              hipStream_t stream) {
  const float* xu = (const float*)d_in[0];
  const float* xn = (const float*)d_in[1];
  const float* xs = (const float*)d_in[2];
  const float* W1 = (const float*)d_in[3];
  const float* b1 = (const float*)d_in[4];
  const float* W2 = (const float*)d_in[5];
  const float* b2 = (const float*)d_in[6];
  const float* Wu = (const float*)d_in[7];
  const float* bu = (const float*)d_in[8];
  const float* Wn = (const float*)d_in[9];
  const float* bn = (const float*)d_in[10];
  const float* Wsrc = (const float*)d_in[11];
  const float* bsrc = (const float*)d_in[12];
  const int* SRC[5] = {(const int*)d_in[13], (const int*)d_in[15], (const int*)d_in[17],
                       (const int*)d_in[19], (const int*)d_in[21]};
  const int* DST[5] = {(const int*)d_in[14], (const int*)d_in[16], (const int*)d_in[18],
                       (const int*)d_in[20], (const int*)d_in[22]};

  // ---- workspace layout (~68.4 MB; padded counters live in d_out scratch) ----
  int* ws_i = (int*)d_ws;
  int* rp = ws_i;                           // 142008
  int* csr = ws_i + 142008;                 // 1400000
  int* pos = ws_i + 1542008;                // 1400000
  int* csums = ws_i + 2942008;              // 320
  float* rs = (float*)(ws_i + 2942328);     // 284000
  unsigned short* wt = (unsigned short*)(rs + 284000);    // 376832
  unsigned short* aggU = wt + 376832;       // 50000*256
  unsigned short* aggN = aggU + 12800000;   // 20000*256
  unsigned short* aggS = aggN + 5120000;    // 2000*128
  unsigned short* xbU = aggS + 256000;      // 50000*128
  unsigned short* xbN = xbU + 6400000;      // 20000*128
  unsigned short* xbS = xbN + 2560000;      // 2000*128

  // wt sub-offsets (hi, lo consecutive per job)
  unsigned short* L1U_h = wt, * L1U_l = wt + 32768;
  unsigned short* L1N_h = wt + 65536, * L1N_l = wt + 98304;
  unsigned short* L1S_h = wt + 131072, * L1S_l = wt + 147456;
  unsigned short* L2U_h = wt + 163840, * L2U_l = wt + 196608;
  unsigned short* L2N_h = wt + 229376, * L2N_l = wt + 262144;
  unsigned short* L2S_h = wt + 294912, * L2S_l = wt + 311296;
  unsigned short* PU_h = wt + 327680, * PU_l = wt + 335872;
  unsigned short* PN_h = wt + 344064, * PN_l = wt + 352256;
  unsigned short* PS_h = wt + 360448, * PS_l = wt + 368640;

  // ---- d_out layout ----
  float* outf = (float*)d_out;
  float* ou = outf;                 // 50000*64
  float* on = outf + 3200000;       // 20000*64
  float* osrc = outf + 4480000;     // 2000*64
  float* hu = outf + 4608000;       // 50000*128
  float* hn = outf + 11008000;      // 20000*128
  float* hs = outf + 13568000;      // 2000*128

  // padded counters (stride-8 ints, 32B/counter) in hu's slot — dead until
  // layer-2 mgemm3 fully overwrites hu. 284000*8 ints = 9.09 MB < 25.6 MB.
  int* cnt = (int*)hu;

  // ---- fused setup: graph count + weight prep + feature convert ----
  hipMemsetAsync(cnt, 0, (size_t)284000 * 8 * 4, stream);
  SetupArgs su;
  for (int r = 0; r < 5; ++r)
    su.rel[r] = {SRC[r], DST[r], cnt + (size_t)DOUT_OFF[r] * 8,
                 cnt + (size_t)DIN_OFF[r] * 8, pos + CSR_OFF[r], REL_E[r]};
  su.pj[0] = {W1, W1 + 2 * 16384, L1U_h, L1U_l, 128, 8, 0};
  su.pj[1] = {W1 + 16384, W1 + 3 * 16384, L1N_h, L1N_l, 128, 8, 128};
  su.pj[2] = {W1 + 4 * 16384, nullptr, L1S_h, L1S_l, 128, 7, 256};
  su.pj[3] = {W2, W2 + 2 * 16384, L2U_h, L2U_l, 128, 8, 320};
  su.pj[4] = {W2 + 16384, W2 + 3 * 16384, L2N_h, L2N_l, 128, 8, 448};
  su.pj[5] = {W2 + 4 * 16384, nullptr, L2S_h, L2S_l, 128, 7, 576};
  su.pj[6] = {Wu, nullptr, PU_h, PU_l, 64, 7, 640};
  su.pj[7] = {Wn, nullptr, PN_h, PN_l, 64, 7, 672};
  su.pj[8] = {Wsrc, nullptr, PS_h, PS_l, 64, 7, 704};
  su.cj[0] = {xu, xbU, kNU * 32, 0};
  su.cj[1] = {xn, xbN, kNN * 32, 6250};
  su.cj[2] = {xs, xbS, kNS * 32, 8750};
  k_setup<<<15206, 256, 0, stream>>>(su);

  // ---- rs + scan ----
  ScanArgs sa;
  for (int r = 0; r < 5; ++r) {
    sa.cnt[r] = cnt + (size_t)DIN_OFF[r] * 8;
    sa.rp[r] = rp + RP_OFF[r];
    sa.n[r] = REL_ND[r];
  }
  sa.csums = csums;
  RsScanArgs rsa;
  rsa.cnt = cnt;
  rsa.rs = rs;
  rsa.sa = sa;
  k_rs_scan1<<<1250, 256, 0, stream>>>(rsa);
  k_scan3<<<140, 256, 0, stream>>>(sa);

  B2Args b2a;
  for (int r = 0; r < 5; ++r)
    b2a.rel[r] = {SRC[r], DST[r], rp + RP_OFF[r], pos + CSR_OFF[r],
                  csr + CSR_OFF[r], REL_E[r]};
  k_build2<<<5470, 256, 0, stream>>>(b2a);

  // ---- hetero layers: gather + fused MFMA GEMM ----
  auto layer = [&](const unsigned short* Uh, const unsigned short* Ul,
                   const unsigned short* Nh, const unsigned short* Nl,
                   const unsigned short* Sh, const unsigned short* Sl,
                   const float* bl, bool last) {
    const unsigned short* XIN[5] = {xbU, xbU, xbN, xbS, xbN};
    unsigned short* OUT[5] = {aggU, aggN, aggU, aggN, aggS};
    const int OSTR[5] = {256, 256, 256, 256, 128};
    const int OOFF[5] = {0, 0, 128, 128, 0};
    GArgs ga;
    for (int r = 0; r < 5; ++r)
      ga.rel[r] = {rp + RP_OFF[r], csr + CSR_OFF[r], XIN[r], rs + DOUT_OFF[r],
                   rs + DIN_OFF[r], OUT[r], OSTR[r], OOFF[r], REL_ND[r]};
    k_gather<<<8875, 256, 0, stream>>>(ga);
    MArgs ma;
    // layer-1 f32 H is dead (layer-2 consumes the bf16 copy) -> H=nullptr
    ma.j[0] = {aggU, Uh, Ul, bl, bl + 2 * 128, 0.5f, 1,
               last ? hu : nullptr, 128, xbU, kNU, 0};
    ma.j[1] = {aggN, Nh, Nl, bl + 128, bl + 3 * 128, 0.5f, 1,
               last ? hn : nullptr, 128, xbN, kNN, 782};
    ma.j[2] = {aggS, Sh, Sl, bl + 4 * 128, nullptr, 1.0f, 1,
               last ? hs : nullptr, 128, xbS, kNS, 1095};
    k_mgemm3<<<1127, 256, 0, stream>>>(ma);
  };

  layer(L1U_h, L1U_l, L1N_h, L1N_l, L1S_h, L1S_l, b1, false);  // x -> h1 (bf16 only)
  layer(L2U_h, L2U_l, L2N_h, L2N_l, L2S_h, L2S_l, b2, true);   // h1 -> h2 (f32 + bf16)

  // ---- output projections (read bf16 h2 from xb*) ----
  MArgs pm;
  pm.j[0] = {xbU, PU_h, PU_l, bu, nullptr, 1.0f, 0, ou, 64, nullptr, kNU, 0};
  pm.j[1] = {xbN, PN_h, PN_l, bn, nullptr, 1.0f, 0, on, 64, nullptr, kNN, 782};
  pm.j[2] = {xbS, PS_h, PS_l, bsrc, nullptr, 1.0f, 0, osrc, 64, nullptr, kNS, 1095};
  k_proj3<<<1127, 256, 0, stream>>>(pm);
}